// Round 1
// baseline (377.485 us; speedup 1.0000x reference)
//
#include <hip/hip_runtime.h>
#include <math.h>

// Problem constants
#define NH 8
#define DDIM 64
#define NN 2
#define QQ 128
#define PPDIM 128
#define BBD 4
#define ROWS 512           // Q*B == P*B
#define EPSN 1e-5f
#define TEMPER 30.0f

// Workspace layout (float offsets)
#define WQ_R 0u            // [H][N][512][64] rows = q*4+b
#define WQ_I 524288u
#define WK_R 1048576u      // rows = p*4+b
#define WK_I 1572864u
#define MU_  2097152u      // [4][16][64]  tensor: 0 wq_r,1 wq_i,2 wk_r,3 wk_i
#define RS_  2101248u
#define VV_  2105344u      // 4 x [H][N][512][64]  (v1,v2,v3,v4)
#define C_R_ 4202496u      // [H][N][512]
#define C_I_ 4210688u
#define ACR_ 4218880u      // [H][N][Q][B][P]
#define ACI_ 5267456u
#define AFF_ 6316032u      // [H][N][Q][B][P]
// total 7364608 floats = ~29.5 MB

#define DOT4(acc, s, v)  { acc = fmaf((s).x,(v).x,acc); acc = fmaf((s).y,(v).y,acc); acc = fmaf((s).z,(v).z,acc); acc = fmaf((s).w,(v).w,acc); }
#define NDOT4(acc, s, v) { acc = fmaf(-(s).x,(v).x,acc); acc = fmaf(-(s).y,(v).y,acc); acc = fmaf(-(s).z,(v).z,acc); acc = fmaf(-(s).w,(v).w,acc); }

// ---------------------------------------------------------------------------
// K1: complex projection (pre-norm).  out_r = inR@Wr^T - inI@Wi^T,
//     out_i = inR@Wi^T + inI@Wr^T.  Linear biases omitted: they are constant
//     per-d over the (rows) axis and cancel exactly under InstanceNorm.
// grid (8 rowtiles, 16 hn), block 256
// ---------------------------------------------------------------------------
__global__ __launch_bounds__(256) void k_proj(
    const float* __restrict__ inR, const float* __restrict__ inI,   // [N,512,64]
    const float* __restrict__ Wr,  const float* __restrict__ Wi,    // [H,64,64]
    float* __restrict__ outR, float* __restrict__ outI)             // [H,N,512,64]
{
    __shared__ float sWT[2][64 * 64];     // transposed: [e][d]
    const int t  = threadIdx.x;
    const int rt = blockIdx.x;
    const int hn = blockIdx.y;
    const int h = hn >> 1, n = hn & 1;
    const float* wr0 = Wr + h * 4096;
    const float* wi0 = Wi + h * 4096;
#pragma unroll
    for (int j = 0; j < 16; ++j) {
        int flat = t + 256 * j;
        int d = flat & 63, e = flat >> 6;           // lanes: d consecutive -> LDS store conflict-free
        sWT[0][e * 64 + d] = wr0[d * 64 + e];
        sWT[1][e * 64 + d] = wi0[d * 64 + e];
    }
    __syncthreads();
    const int row = t & 63, dq = t >> 6;
    const int rowg = rt * 64 + row;
    const float4* xr4 = (const float4*)(inR + (n * ROWS + rowg) * 64);
    const float4* xi4 = (const float4*)(inI + (n * ROWS + rowg) * 64);
    float ar[16], ai[16];
#pragma unroll
    for (int j = 0; j < 16; ++j) { ar[j] = 0.f; ai[j] = 0.f; }
    for (int ec = 0; ec < 16; ++ec) {
        float4 xrv = xr4[ec], xiv = xi4[ec];
        float xrs[4] = {xrv.x, xrv.y, xrv.z, xrv.w};
        float xis[4] = {xiv.x, xiv.y, xiv.z, xiv.w};
#pragma unroll
        for (int u = 0; u < 4; ++u) {
            int e = ec * 4 + u;
            const float4* wrp = (const float4*)&sWT[0][e * 64 + dq * 16];
            const float4* wip = (const float4*)&sWT[1][e * 64 + dq * 16];
            float xr = xrs[u], xi = xis[u];
#pragma unroll
            for (int j4 = 0; j4 < 4; ++j4) {
                float4 wr = wrp[j4], wi = wip[j4];
                ar[j4*4+0] = fmaf(xr, wr.x, fmaf(-xi, wi.x, ar[j4*4+0]));
                ar[j4*4+1] = fmaf(xr, wr.y, fmaf(-xi, wi.y, ar[j4*4+1]));
                ar[j4*4+2] = fmaf(xr, wr.z, fmaf(-xi, wi.z, ar[j4*4+2]));
                ar[j4*4+3] = fmaf(xr, wr.w, fmaf(-xi, wi.w, ar[j4*4+3]));
                ai[j4*4+0] = fmaf(xr, wi.x, fmaf( xi, wr.x, ai[j4*4+0]));
                ai[j4*4+1] = fmaf(xr, wi.y, fmaf( xi, wr.y, ai[j4*4+1]));
                ai[j4*4+2] = fmaf(xr, wi.z, fmaf( xi, wr.z, ai[j4*4+2]));
                ai[j4*4+3] = fmaf(xr, wi.w, fmaf( xi, wr.w, ai[j4*4+3]));
            }
        }
    }
    float* oR = outR + (hn * ROWS + rowg) * 64 + dq * 16;
    float* oI = outI + (hn * ROWS + rowg) * 64 + dq * 16;
#pragma unroll
    for (int j4 = 0; j4 < 4; ++j4) {
        ((float4*)oR)[j4] = make_float4(ar[j4*4+0], ar[j4*4+1], ar[j4*4+2], ar[j4*4+3]);
        ((float4*)oI)[j4] = make_float4(ai[j4*4+0], ai[j4*4+1], ai[j4*4+2], ai[j4*4+3]);
    }
}

// ---------------------------------------------------------------------------
// K2: InstanceNorm stats per (tensor, h, n, d) over 512 rows.  biased var.
// grid 64 (= 4 tensors * 16 hn), block 256
// ---------------------------------------------------------------------------
__global__ __launch_bounds__(256) void k_stats(
    const float* __restrict__ base, float* __restrict__ mu, float* __restrict__ rs)
{
    __shared__ float sS[4][64], sQ[4][64];
    const int bid = blockIdx.x, ti = bid >> 4, hn = bid & 15;
    const float* X = base + (unsigned)ti * 524288u + hn * ROWS * 64;
    const int t = threadIdx.x, d = t & 63, part = t >> 6;
    float s = 0.f, sq = 0.f;
    for (int r = 0; r < 128; ++r) {
        float x = X[(part * 128 + r) * 64 + d];
        s += x; sq = fmaf(x, x, sq);
    }
    sS[part][d] = s; sQ[part][d] = sq;
    __syncthreads();
    if (t < 64) {
        float st = sS[0][t] + sS[1][t] + sS[2][t] + sS[3][t];
        float qt = sQ[0][t] + sQ[1][t] + sQ[2][t] + sQ[3][t];
        float m = st * (1.f / 512.f);
        float var = qt * (1.f / 512.f) - m * m;
        mu[(ti * 16 + hn) * 64 + t] = m;
        rs[(ti * 16 + hn) * 64 + t] = rsqrtf(var + EPSN);
    }
}

// ---------------------------------------------------------------------------
// K3: v-vectors v1..v4 = {WKRr,WKRi}^T {wr_qr, wr_qi}, and bias dot terms
//     c_r = <br-bi, wr_qr> - <br+bi, wr_qi>, c_i = <br-bi, wr_qi> + <br+bi, wr_qr>
// grid (8 rowtiles, 16 hn), block 256
// ---------------------------------------------------------------------------
__global__ __launch_bounds__(256) void k_vvec(
    const float* __restrict__ wqr, const float* __restrict__ wqi,
    const float* __restrict__ mu,  const float* __restrict__ rs,
    const float* __restrict__ Ar,  const float* __restrict__ Ai,   // WKRr_w, WKRi_w
    const float* __restrict__ Abr, const float* __restrict__ Abi,  // WKRr_b, WKRi_b
    const float* __restrict__ gr,  const float* __restrict__ btr,  // wr_r affine
    const float* __restrict__ gi,  const float* __restrict__ bti,  // wr_i affine
    float* __restrict__ Vout, float* __restrict__ cR, float* __restrict__ cI)
{
    __shared__ float sW[2][4096];       // plain [d][e]
    __shared__ float sX[2][64][64];     // transposed: [d][row]
    const int t = threadIdx.x;
    const int rt = blockIdx.x, hn = blockIdx.y, h = hn >> 1;
    const float* a0 = Ar + h * 4096;
    const float* a1 = Ai + h * 4096;
#pragma unroll
    for (int j = 0; j < 16; ++j) {
        int flat = t + 256 * j;
        sW[0][flat] = a0[flat];
        sW[1][flat] = a1[flat];
    }
    const float* mu0 = mu + hn * 64;        const float* rs0 = rs + hn * 64;
    const float* mu1 = mu + (16 + hn) * 64; const float* rs1 = rs + (16 + hn) * 64;
#pragma unroll
    for (int j = 0; j < 16; ++j) {
        int flat = t + 256 * j;
        int d = flat >> 6, row = flat & 63;         // d wave-uniform -> scalar stat loads
        int gidx = (hn * ROWS + rt * 64 + row) * 64 + d;
        float xr = wqr[gidx], xi = wqi[gidx];
        sX[0][d][row] = (xr - mu0[d]) * rs0[d] * gr[h * 64 + d] + btr[h * 64 + d];
        sX[1][d][row] = (xi - mu1[d]) * rs1[d] * gi[h * 64 + d] + bti[h * 64 + d];
    }
    __syncthreads();
    const int row = t & 63, eq = t >> 6;
    float v[4][16];
#pragma unroll
    for (int k = 0; k < 4; ++k)
#pragma unroll
        for (int j = 0; j < 16; ++j) v[k][j] = 0.f;
    for (int d = 0; d < 64; ++d) {
        float xr = sX[0][d][row], xi = sX[1][d][row];
#pragma unroll
        for (int j4 = 0; j4 < 4; ++j4) {
            float4 wr = *(const float4*)&sW[0][d * 64 + eq * 16 + j4 * 4];
            float4 wi = *(const float4*)&sW[1][d * 64 + eq * 16 + j4 * 4];
            v[0][j4*4+0] = fmaf(xr, wr.x, v[0][j4*4+0]); v[0][j4*4+1] = fmaf(xr, wr.y, v[0][j4*4+1]);
            v[0][j4*4+2] = fmaf(xr, wr.z, v[0][j4*4+2]); v[0][j4*4+3] = fmaf(xr, wr.w, v[0][j4*4+3]);
            v[1][j4*4+0] = fmaf(xr, wi.x, v[1][j4*4+0]); v[1][j4*4+1] = fmaf(xr, wi.y, v[1][j4*4+1]);
            v[1][j4*4+2] = fmaf(xr, wi.z, v[1][j4*4+2]); v[1][j4*4+3] = fmaf(xr, wi.w, v[1][j4*4+3]);
            v[2][j4*4+0] = fmaf(xi, wr.x, v[2][j4*4+0]); v[2][j4*4+1] = fmaf(xi, wr.y, v[2][j4*4+1]);
            v[2][j4*4+2] = fmaf(xi, wr.z, v[2][j4*4+2]); v[2][j4*4+3] = fmaf(xi, wr.w, v[2][j4*4+3]);
            v[3][j4*4+0] = fmaf(xi, wi.x, v[3][j4*4+0]); v[3][j4*4+1] = fmaf(xi, wi.y, v[3][j4*4+1]);
            v[3][j4*4+2] = fmaf(xi, wi.z, v[3][j4*4+2]); v[3][j4*4+3] = fmaf(xi, wi.w, v[3][j4*4+3]);
        }
    }
    const int rowg = rt * 64 + row;
#pragma unroll
    for (int k = 0; k < 4; ++k) {
        float* o = Vout + (unsigned)k * 524288u + (hn * ROWS + rowg) * 64 + eq * 16;
#pragma unroll
        for (int j4 = 0; j4 < 4; ++j4)
            ((float4*)o)[j4] = make_float4(v[k][j4*4+0], v[k][j4*4+1], v[k][j4*4+2], v[k][j4*4+3]);
    }
    if (t < 64) {
        const int rw = t;
        float cr = 0.f, ci = 0.f;
        for (int d = 0; d < 64; ++d) {
            float br = Abr[h * 64 + d], bi = Abi[h * 64 + d];
            float bm = br - bi, bp = br + bi;
            float xr = sX[0][d][rw], xi = sX[1][d][rw];
            cr = fmaf(bm, xr, fmaf(-bp, xi, cr));
            ci = fmaf(bm, xi, fmaf( bp, xr, ci));
        }
        cR[hn * ROWS + rt * 64 + rw] = cr;
        cI[hn * ROWS + rt * 64 + rw] = ci;
    }
}

// ---------------------------------------------------------------------------
// K4: AC scores.  AC_r[q,p] = nk_r[p]·wwqr[q] - nk_i[p]·wwqi[q]
//                 AC_i[q,p] = nk_r[p]·wwqi[q] + nk_i[p]·wwqr[q]
// InstanceNorm applied on-the-fly while staging to LDS.
// grid (8 = qt(4)+4*ph(2), 16 hn, 4 b), block 256
// ---------------------------------------------------------------------------
__global__ __launch_bounds__(256) void k_ac(
    const float* __restrict__ wqr, const float* __restrict__ wqi,
    const float* __restrict__ wkr, const float* __restrict__ wki,
    const float* __restrict__ mu,  const float* __restrict__ rs,
    const float* __restrict__ gwr, const float* __restrict__ btwr,
    const float* __restrict__ gwi, const float* __restrict__ btwi,
    float* __restrict__ ACr, float* __restrict__ ACi)
{
    __shared__ float sK[2][64][65];     // [p][e] padded
    __shared__ float sQT[2][64][36];    // [d][qlocal] transposed, padded for f4 align
    const int t = threadIdx.x;
    const int bx = blockIdx.x, qt = bx & 3, ph = bx >> 2;
    const int hn = blockIdx.y, h = hn >> 1;
    const int b = blockIdx.z;
    const float* mu2 = mu + (32 + hn) * 64; const float* rs2 = rs + (32 + hn) * 64;
    const float* mu3 = mu + (48 + hn) * 64; const float* rs3 = rs + (48 + hn) * 64;
#pragma unroll
    for (int j = 0; j < 4; ++j) {
        int flat4 = t + 256 * j;
        int word = flat4 * 4;
        int pp = word >> 6, ee = word & 63;
        int gidx = (hn * ROWS + (ph * 64 + pp) * 4 + b) * 64 + ee;
        float4 kr = *(const float4*)&wkr[gidx];
        float4 ki = *(const float4*)&wki[gidx];
        float4 m2 = *(const float4*)&mu2[ee]; float4 r2 = *(const float4*)&rs2[ee];
        float4 m3 = *(const float4*)&mu3[ee]; float4 r3 = *(const float4*)&rs3[ee];
        sK[0][pp][ee+0] = (kr.x - m2.x) * r2.x; sK[0][pp][ee+1] = (kr.y - m2.y) * r2.y;
        sK[0][pp][ee+2] = (kr.z - m2.z) * r2.z; sK[0][pp][ee+3] = (kr.w - m2.w) * r2.w;
        sK[1][pp][ee+0] = (ki.x - m3.x) * r3.x; sK[1][pp][ee+1] = (ki.y - m3.y) * r3.y;
        sK[1][pp][ee+2] = (ki.z - m3.z) * r3.z; sK[1][pp][ee+3] = (ki.w - m3.w) * r3.w;
    }
    const float* mu0 = mu + hn * 64;        const float* rs0 = rs + hn * 64;
    const float* mu1 = mu + (16 + hn) * 64; const float* rs1 = rs + (16 + hn) * 64;
#pragma unroll
    for (int j = 0; j < 2; ++j) {
        int flat4 = t + 256 * j;
        int word = flat4 * 4;
        int qq = word >> 6, dd = word & 63;
        int gidx = (hn * ROWS + (qt * 32 + qq) * 4 + b) * 64 + dd;
        float4 xr = *(const float4*)&wqr[gidx];
        float4 xi = *(const float4*)&wqi[gidx];
        float4 m0 = *(const float4*)&mu0[dd]; float4 r0 = *(const float4*)&rs0[dd];
        float4 m1 = *(const float4*)&mu1[dd]; float4 r1 = *(const float4*)&rs1[dd];
        float4 g0 = *(const float4*)&gwr[h * 64 + dd]; float4 b0 = *(const float4*)&btwr[h * 64 + dd];
        float4 g1 = *(const float4*)&gwi[h * 64 + dd]; float4 b1 = *(const float4*)&btwi[h * 64 + dd];
        sQT[0][dd+0][qq] = fmaf((xr.x - m0.x) * r0.x, g0.x, b0.x);
        sQT[0][dd+1][qq] = fmaf((xr.y - m0.y) * r0.y, g0.y, b0.y);
        sQT[0][dd+2][qq] = fmaf((xr.z - m0.z) * r0.z, g0.z, b0.z);
        sQT[0][dd+3][qq] = fmaf((xr.w - m0.w) * r0.w, g0.w, b0.w);
        sQT[1][dd+0][qq] = fmaf((xi.x - m1.x) * r1.x, g1.x, b1.x);
        sQT[1][dd+1][qq] = fmaf((xi.y - m1.y) * r1.y, g1.y, b1.y);
        sQT[1][dd+2][qq] = fmaf((xi.z - m1.z) * r1.z, g1.z, b1.z);
        sQT[1][dd+3][qq] = fmaf((xi.w - m1.w) * r1.w, g1.w, b1.w);
    }
    __syncthreads();
    const int p = t & 63, qs = t >> 6;
    float acr[8], aci[8];
#pragma unroll
    for (int j = 0; j < 8; ++j) { acr[j] = 0.f; aci[j] = 0.f; }
    for (int e = 0; e < 64; ++e) {
        float kr = sK[0][p][e], ki = sK[1][p][e];
#pragma unroll
        for (int j4 = 0; j4 < 2; ++j4) {
            float4 qr = *(const float4*)&sQT[0][e][qs * 8 + j4 * 4];
            float4 qi = *(const float4*)&sQT[1][e][qs * 8 + j4 * 4];
            acr[j4*4+0] = fmaf(kr, qr.x, fmaf(-ki, qi.x, acr[j4*4+0]));
            acr[j4*4+1] = fmaf(kr, qr.y, fmaf(-ki, qi.y, acr[j4*4+1]));
            acr[j4*4+2] = fmaf(kr, qr.z, fmaf(-ki, qi.z, acr[j4*4+2]));
            acr[j4*4+3] = fmaf(kr, qr.w, fmaf(-ki, qi.w, acr[j4*4+3]));
            aci[j4*4+0] = fmaf(kr, qi.x, fmaf( ki, qr.x, aci[j4*4+0]));
            aci[j4*4+1] = fmaf(kr, qi.y, fmaf( ki, qr.y, aci[j4*4+1]));
            aci[j4*4+2] = fmaf(kr, qi.z, fmaf( ki, qr.z, aci[j4*4+2]));
            aci[j4*4+3] = fmaf(kr, qi.w, fmaf( ki, qr.w, aci[j4*4+3]));
        }
    }
#pragma unroll
    for (int j = 0; j < 8; ++j) {
        int q = qt * 32 + qs * 8 + j;
        int oidx = ((hn * 128 + q) * 4 + b) * 128 + ph * 64 + p;
        ACr[oidx] = acr[j];
        ACi[oidx] = aci[j];
    }
}

// ---------------------------------------------------------------------------
// K5: fused BD + AC combine + sqrt-affinity + softmax over b.
// BD_r[q,p] = ERqp·v1 - EIqp·v2 - ERpq·v4 - EIpq·v3 + c_r
// BD_i[q,p] = ERqp·v3 - EIqp·v4 + ERpq·v2 + EIpq·v1 + c_i
// grid (2 phalf, 256 nq), block 256 (thread: b = t&3, p = ph*64 + t>>2)
// ---------------------------------------------------------------------------
__global__ __launch_bounds__(256) void k_bd(
    const float* __restrict__ ER, const float* __restrict__ EI,
    const float* __restrict__ Vv, const float* __restrict__ cR, const float* __restrict__ cI,
    const float* __restrict__ ACr, const float* __restrict__ ACi,
    float* __restrict__ AFF)
{
    __shared__ float sV[8 * 4 * 260];   // per (h,b): v1|v2|v3|v4 (4*64) + pad 4
    __shared__ float sC[8][4][2];
    const int t = threadIdx.x;
    const int ph = blockIdx.x;
    const int nq = blockIdx.y;
    const int n = nq >> 7, q = nq & 127;
#pragma unroll
    for (int j = 0; j < 8; ++j) {
        int flat4 = t + 256 * j;
        int word = flat4 * 4;
        int e = word & 63, k = (word >> 6) & 3, bb = (word >> 8) & 3, h = word >> 10;
        float4 x = *(const float4*)&Vv[(unsigned)k * 524288u + ((h * 2 + n) * ROWS + q * 4 + bb) * 64 + e];
        *(float4*)&sV[(h * 4 + bb) * 260 + k * 64 + e] = x;
    }
    if (t < 64) {
        int h = t >> 3, bb = (t >> 1) & 3, ri = t & 1;
        const float* c = ri ? cI : cR;
        sC[h][bb][ri] = c[(h * 2 + n) * ROWS + q * 4 + bb];
    }
    __syncthreads();
    const int b = t & 3, p = ph * 64 + (t >> 2);
    const float4* eqp_r = (const float4*)(ER + ((((n * 128 + q) * 128 + p) * 4 + b) * 64));
    const float4* eqp_i = (const float4*)(EI + ((((n * 128 + q) * 128 + p) * 4 + b) * 64));
    const float4* epq_r = (const float4*)(ER + ((((n * 128 + p) * 128 + q) * 4 + b) * 64));
    const float4* epq_i = (const float4*)(EI + ((((n * 128 + p) * 128 + q) * 4 + b) * 64));
    float bdr[8], bdi[8];
#pragma unroll
    for (int h = 0; h < 8; ++h) { bdr[h] = 0.f; bdi[h] = 0.f; }
    for (int ec = 0; ec < 16; ++ec) {
        float4 a  = eqp_r[ec];
        float4 bv = eqp_i[ec];
        float4 c4 = epq_r[ec];
        float4 d4 = epq_i[ec];
#pragma unroll
        for (int h = 0; h < 8; ++h) {
            const float* base = &sV[(h * 4 + b) * 260 + ec * 4];
            float4 v1 = *(const float4*)(base);
            float4 v2 = *(const float4*)(base + 64);
            float4 v3 = *(const float4*)(base + 128);
            float4 v4 = *(const float4*)(base + 192);
            DOT4 (bdr[h], a,  v1);
            NDOT4(bdr[h], bv, v2);
            NDOT4(bdr[h], c4, v4);
            NDOT4(bdr[h], d4, v3);
            DOT4 (bdi[h], a,  v3);
            NDOT4(bdi[h], bv, v4);
            DOT4 (bdi[h], c4, v2);
            DOT4 (bdi[h], d4, v1);
        }
    }
#pragma unroll
    for (int h = 0; h < 8; ++h) {
        float r  = bdr[h] + sC[h][b][0];
        float im = bdi[h] + sC[h][b][1];
        int oidx = (((h * 2 + n) * 128 + q) * 4 + b) * 128 + p;
        float ar = ACr[oidx], ai = ACi[oidx];
        float aff = sqrtf(fmaf(ar, ar, ai * ai)) + sqrtf(fmaf(r, r, im * im));
        float logit = aff * TEMPER;
        float m = fmaxf(logit, __shfl_xor(logit, 1));
        m = fmaxf(m, __shfl_xor(m, 2));
        float ex = __expf(logit - m);
        float s = ex + __shfl_xor(ex, 1);
        s = s + __shfl_xor(s, 2);
        AFF[oidx] = ex / s;
    }
}

// ---------------------------------------------------------------------------
// K6: PV contraction over p; writes final concatenated outputs.
// grid 1024 (= N*Q*B), block 512 (thread: h = t>>6, d = t&63)
// ---------------------------------------------------------------------------
__global__ __launch_bounds__(512) void k_pv(
    const float* __restrict__ AFF,
    const float* __restrict__ Vr, const float* __restrict__ Vi,
    float* __restrict__ out)
{
    __shared__ float sA[8][128];
    const int t = threadIdx.x;
    const int nqb = blockIdx.x;
    const int b = nqb & 3, q = (nqb >> 2) & 127, n = nqb >> 9;
#pragma unroll
    for (int j = 0; j < 2; ++j) {
        int flat = t + 512 * j;
        int hh = flat >> 7, p = flat & 127;
        sA[hh][p] = AFF[(((hh * 2 + n) * 128 + q) * 4 + b) * 128 + p];
    }
    __syncthreads();
    const int h = t >> 6, d = t & 63;
    const float* vr = Vr + (n * 128 * 4 + b) * 64 + d;
    const float* vi = Vi + (n * 128 * 4 + b) * 64 + d;
    float o_r = 0.f, o_i = 0.f;
#pragma unroll 4
    for (int p = 0; p < 128; ++p) {
        float a = sA[h][p];
        o_r = fmaf(a, vr[p * 256], o_r);
        o_i = fmaf(a, vi[p * 256], o_i);
    }
    int oidx = ((n * 128 + q) * 4 + b) * 512 + h * 64 + d;
    out[oidx] = o_r;
    out[524288 + oidx] = o_i;
}

// ---------------------------------------------------------------------------
extern "C" void kernel_launch(void* const* d_in, const int* in_sizes, int n_in,
                              void* d_out, int out_size, void* d_ws, size_t ws_size,
                              hipStream_t stream) {
    (void)in_sizes; (void)n_in; (void)out_size; (void)ws_size;
    const float* q_r  = (const float*)d_in[0];
    const float* q_i  = (const float*)d_in[1];
    const float* k_r  = (const float*)d_in[2];
    const float* k_i  = (const float*)d_in[3];
    const float* v_r  = (const float*)d_in[4];
    const float* v_i  = (const float*)d_in[5];
    const float* e_r  = (const float*)d_in[6];
    const float* e_i  = (const float*)d_in[7];
    const float* WKr_w  = (const float*)d_in[8];
    const float* WKi_w  = (const float*)d_in[10];
    const float* WKRr_w = (const float*)d_in[12];
    const float* WKRr_b = (const float*)d_in[13];
    const float* WKRi_w = (const float*)d_in[14];
    const float* WKRi_b = (const float*)d_in[15];
    const float* WQr_w  = (const float*)d_in[16];
    const float* WQi_w  = (const float*)d_in[18];
    const float* ww_r_g  = (const float*)d_in[20];
    const float* ww_r_bt = (const float*)d_in[21];
    const float* ww_i_g  = (const float*)d_in[22];
    const float* ww_i_bt = (const float*)d_in[23];
    const float* wr_r_g  = (const float*)d_in[24];
    const float* wr_r_bt = (const float*)d_in[25];
    const float* wr_i_g  = (const float*)d_in[26];
    const float* wr_i_bt = (const float*)d_in[27];
    float* ws  = (float*)d_ws;
    float* out = (float*)d_out;

    k_proj<<<dim3(8, 16), 256, 0, stream>>>(q_r, q_i, WQr_w, WQi_w, ws + WQ_R, ws + WQ_I);
    k_proj<<<dim3(8, 16), 256, 0, stream>>>(k_r, k_i, WKr_w, WKi_w, ws + WK_R, ws + WK_I);
    k_stats<<<64, 256, 0, stream>>>(ws + WQ_R, ws + MU_, ws + RS_);
    k_vvec<<<dim3(8, 16), 256, 0, stream>>>(ws + WQ_R, ws + WQ_I, ws + MU_, ws + RS_,
                                            WKRr_w, WKRi_w, WKRr_b, WKRi_b,
                                            wr_r_g, wr_r_bt, wr_i_g, wr_i_bt,
                                            ws + VV_, ws + C_R_, ws + C_I_);
    k_ac<<<dim3(8, 16, 4), 256, 0, stream>>>(ws + WQ_R, ws + WQ_I, ws + WK_R, ws + WK_I,
                                             ws + MU_, ws + RS_,
                                             ww_r_g, ww_r_bt, ww_i_g, ww_i_bt,
                                             ws + ACR_, ws + ACI_);
    k_bd<<<dim3(2, 256), 256, 0, stream>>>(e_r, e_i, ws + VV_, ws + C_R_, ws + C_I_,
                                           ws + ACR_, ws + ACI_, ws + AFF_);
    k_pv<<<1024, 512, 0, stream>>>(ws + AFF_, v_r, v_i, out);
}

// Round 2
// 290.904 us; speedup vs baseline: 1.2976x; 1.2976x over previous
//
#include <hip/hip_runtime.h>
#include <math.h>

// Problem constants
#define NH 8
#define DDIM 64
#define NN 2
#define QQ 128
#define PPDIM 128
#define BBD 4
#define ROWS 512           // Q*B == P*B
#define EPSN 1e-5f
#define TEMPER 30.0f

// Workspace layout (float offsets)
#define WQ_R 0u            // [H][N][512][64] rows = q*4+b
#define WQ_I 524288u
#define WK_R 1048576u      // rows = p*4+b
#define WK_I 1572864u
#define MU_  2097152u      // [4][16][64]  tensor: 0 wq_r,1 wq_i,2 wk_r,3 wk_i
#define RS_  2101248u
#define VV_  2105344u      // 4 x [H][N][512][64]  (v1,v2,v3,v4)
#define C_R_ 4202496u      // [H][N][512]
#define C_I_ 4210688u
#define ACR_ 4218880u      // [H][N][Q][B][P]
#define ACI_ 5267456u
#define AFF_ 6316032u      // [H][N][Q][B][P]
// total 7364608 floats = ~29.5 MB

#define DOT4(acc, s, v)  { acc = fmaf((s).x,(v).x,acc); acc = fmaf((s).y,(v).y,acc); acc = fmaf((s).z,(v).z,acc); acc = fmaf((s).w,(v).w,acc); }
#define NDOT4(acc, s, v) { acc = fmaf(-(s).x,(v).x,acc); acc = fmaf(-(s).y,(v).y,acc); acc = fmaf(-(s).z,(v).z,acc); acc = fmaf(-(s).w,(v).w,acc); }

// ---------------------------------------------------------------------------
// K1: complex projection (pre-norm), q and k in one launch (grid.z).
//     out_r = inR@Wr^T - inI@Wi^T, out_i = inR@Wi^T + inI@Wr^T.
//     Linear biases omitted: constant per-d over rows, cancel under InstanceNorm.
// grid (8 rowtiles, 16 hn, 2 qk), block 256
// ---------------------------------------------------------------------------
__global__ __launch_bounds__(256) void k_proj(
    const float* __restrict__ qR, const float* __restrict__ qI,
    const float* __restrict__ kR, const float* __restrict__ kI,
    const float* __restrict__ WQr, const float* __restrict__ WQi,
    const float* __restrict__ WKr, const float* __restrict__ WKi,
    float* __restrict__ ws)
{
    __shared__ float sWT[2][64 * 64];     // transposed: [e][d]
    const int t  = threadIdx.x;
    const int rt = blockIdx.x;
    const int hn = blockIdx.y;
    const int z  = blockIdx.z;
    const int h = hn >> 1, n = hn & 1;
    const float* inR = z ? kR : qR;
    const float* inI = z ? kI : qI;
    const float* wr0 = (z ? WKr : WQr) + h * 4096;
    const float* wi0 = (z ? WKi : WQi) + h * 4096;
    float* outR = ws + (z ? WK_R : WQ_R);
    float* outI = ws + (z ? WK_I : WQ_I);
#pragma unroll
    for (int j = 0; j < 16; ++j) {
        int flat = t + 256 * j;
        int d = flat & 63, e = flat >> 6;
        sWT[0][e * 64 + d] = wr0[d * 64 + e];
        sWT[1][e * 64 + d] = wi0[d * 64 + e];
    }
    __syncthreads();
    const int row = t & 63, dq = t >> 6;
    const int rowg = rt * 64 + row;
    const float4* xr4 = (const float4*)(inR + (n * ROWS + rowg) * 64);
    const float4* xi4 = (const float4*)(inI + (n * ROWS + rowg) * 64);
    float ar[16], ai[16];
#pragma unroll
    for (int j = 0; j < 16; ++j) { ar[j] = 0.f; ai[j] = 0.f; }
    for (int ec = 0; ec < 16; ++ec) {
        float4 xrv = xr4[ec], xiv = xi4[ec];
        float xrs[4] = {xrv.x, xrv.y, xrv.z, xrv.w};
        float xis[4] = {xiv.x, xiv.y, xiv.z, xiv.w};
#pragma unroll
        for (int u = 0; u < 4; ++u) {
            int e = ec * 4 + u;
            const float4* wrp = (const float4*)&sWT[0][e * 64 + dq * 16];
            const float4* wip = (const float4*)&sWT[1][e * 64 + dq * 16];
            float xr = xrs[u], xi = xis[u];
#pragma unroll
            for (int j4 = 0; j4 < 4; ++j4) {
                float4 wr = wrp[j4], wi = wip[j4];
                ar[j4*4+0] = fmaf(xr, wr.x, fmaf(-xi, wi.x, ar[j4*4+0]));
                ar[j4*4+1] = fmaf(xr, wr.y, fmaf(-xi, wi.y, ar[j4*4+1]));
                ar[j4*4+2] = fmaf(xr, wr.z, fmaf(-xi, wi.z, ar[j4*4+2]));
                ar[j4*4+3] = fmaf(xr, wr.w, fmaf(-xi, wi.w, ar[j4*4+3]));
                ai[j4*4+0] = fmaf(xr, wi.x, fmaf( xi, wr.x, ai[j4*4+0]));
                ai[j4*4+1] = fmaf(xr, wi.y, fmaf( xi, wr.y, ai[j4*4+1]));
                ai[j4*4+2] = fmaf(xr, wi.z, fmaf( xi, wr.z, ai[j4*4+2]));
                ai[j4*4+3] = fmaf(xr, wi.w, fmaf( xi, wr.w, ai[j4*4+3]));
            }
        }
    }
    float* oR = outR + ((unsigned)hn * ROWS + rowg) * 64 + dq * 16;
    float* oI = outI + ((unsigned)hn * ROWS + rowg) * 64 + dq * 16;
#pragma unroll
    for (int j4 = 0; j4 < 4; ++j4) {
        ((float4*)oR)[j4] = make_float4(ar[j4*4+0], ar[j4*4+1], ar[j4*4+2], ar[j4*4+3]);
        ((float4*)oI)[j4] = make_float4(ai[j4*4+0], ai[j4*4+1], ai[j4*4+2], ai[j4*4+3]);
    }
}

// ---------------------------------------------------------------------------
// K2: InstanceNorm stats per (tensor, h, n, d) over 512 rows.  biased var.
// grid 64 (= 4 tensors * 16 hn), block 256
// ---------------------------------------------------------------------------
__global__ __launch_bounds__(256) void k_stats(
    const float* __restrict__ base, float* __restrict__ mu, float* __restrict__ rs)
{
    __shared__ float sS[4][64], sQ[4][64];
    const int bid = blockIdx.x, ti = bid >> 4, hn = bid & 15;
    const float* X = base + (unsigned)ti * 524288u + hn * ROWS * 64;
    const int t = threadIdx.x, d = t & 63, part = t >> 6;
    float s = 0.f, sq = 0.f;
    for (int r = 0; r < 128; ++r) {
        float x = X[(part * 128 + r) * 64 + d];
        s += x; sq = fmaf(x, x, sq);
    }
    sS[part][d] = s; sQ[part][d] = sq;
    __syncthreads();
    if (t < 64) {
        float st = sS[0][t] + sS[1][t] + sS[2][t] + sS[3][t];
        float qt = sQ[0][t] + sQ[1][t] + sQ[2][t] + sQ[3][t];
        float m = st * (1.f / 512.f);
        float var = qt * (1.f / 512.f) - m * m;
        mu[(ti * 16 + hn) * 64 + t] = m;
        rs[(ti * 16 + hn) * 64 + t] = rsqrtf(var + EPSN);
    }
}

// ---------------------------------------------------------------------------
// K3: v-vectors v1..v4 = {WKRr,WKRi}^T {wr_qr, wr_qi}, and bias dot terms.
// Coalesced staging + XOR-swizzled LDS transpose (stay at 64 KB LDS).
// grid (8 rowtiles, 16 hn), block 256
// ---------------------------------------------------------------------------
#define SXI(dd, rr) ((dd) * 64 + (((rr) + (dd)) & 63))

__global__ __launch_bounds__(256) void k_vvec(
    const float* __restrict__ wqr, const float* __restrict__ wqi,
    const float* __restrict__ mu,  const float* __restrict__ rs,
    const float* __restrict__ Ar,  const float* __restrict__ Ai,
    const float* __restrict__ Abr, const float* __restrict__ Abi,
    const float* __restrict__ gr,  const float* __restrict__ btr,
    const float* __restrict__ gi,  const float* __restrict__ bti,
    float* __restrict__ Vout, float* __restrict__ cR, float* __restrict__ cI)
{
    __shared__ float sW[2][4096];       // plain [d][e]
    __shared__ float sX[2][4096];       // swizzled transpose [d][row]
    const int t = threadIdx.x;
    const int rt = blockIdx.x, hn = blockIdx.y, h = hn >> 1;
    const float* a0 = Ar + h * 4096;
    const float* a1 = Ai + h * 4096;
#pragma unroll
    for (int j = 0; j < 16; ++j) {
        int flat = t + 256 * j;
        sW[0][flat] = a0[flat];
        sW[1][flat] = a1[flat];
    }
    const float* mu0 = mu + hn * 64;        const float* rs0 = rs + hn * 64;
    const float* mu1 = mu + (16 + hn) * 64; const float* rs1 = rs + (16 + hn) * 64;
    {
        const int d = t & 63;            // consecutive lanes -> consecutive d (coalesced)
        const float m0 = mu0[d], r0 = rs0[d], g0 = gr[h * 64 + d], b0 = btr[h * 64 + d];
        const float m1 = mu1[d], r1 = rs1[d], g1 = gi[h * 64 + d], b1 = bti[h * 64 + d];
#pragma unroll
        for (int j = 0; j < 16; ++j) {
            int row = (t >> 6) + 4 * j;
            int gidx = (hn * ROWS + rt * 64 + row) * 64 + d;
            float xr = wqr[gidx], xi = wqi[gidx];
            sX[0][SXI(d, row)] = (xr - m0) * r0 * g0 + b0;
            sX[1][SXI(d, row)] = (xi - m1) * r1 * g1 + b1;
        }
    }
    __syncthreads();
    const int row = t & 63, eq = t >> 6;
    float v[4][16];
#pragma unroll
    for (int k = 0; k < 4; ++k)
#pragma unroll
        for (int j = 0; j < 16; ++j) v[k][j] = 0.f;
    for (int d = 0; d < 64; ++d) {
        float xr = sX[0][SXI(d, row)], xi = sX[1][SXI(d, row)];
#pragma unroll
        for (int j4 = 0; j4 < 4; ++j4) {
            float4 wr = *(const float4*)&sW[0][d * 64 + eq * 16 + j4 * 4];
            float4 wi = *(const float4*)&sW[1][d * 64 + eq * 16 + j4 * 4];
            v[0][j4*4+0] = fmaf(xr, wr.x, v[0][j4*4+0]); v[0][j4*4+1] = fmaf(xr, wr.y, v[0][j4*4+1]);
            v[0][j4*4+2] = fmaf(xr, wr.z, v[0][j4*4+2]); v[0][j4*4+3] = fmaf(xr, wr.w, v[0][j4*4+3]);
            v[1][j4*4+0] = fmaf(xr, wi.x, v[1][j4*4+0]); v[1][j4*4+1] = fmaf(xr, wi.y, v[1][j4*4+1]);
            v[1][j4*4+2] = fmaf(xr, wi.z, v[1][j4*4+2]); v[1][j4*4+3] = fmaf(xr, wi.w, v[1][j4*4+3]);
            v[2][j4*4+0] = fmaf(xi, wr.x, v[2][j4*4+0]); v[2][j4*4+1] = fmaf(xi, wr.y, v[2][j4*4+1]);
            v[2][j4*4+2] = fmaf(xi, wr.z, v[2][j4*4+2]); v[2][j4*4+3] = fmaf(xi, wr.w, v[2][j4*4+3]);
            v[3][j4*4+0] = fmaf(xi, wi.x, v[3][j4*4+0]); v[3][j4*4+1] = fmaf(xi, wi.y, v[3][j4*4+1]);
            v[3][j4*4+2] = fmaf(xi, wi.z, v[3][j4*4+2]); v[3][j4*4+3] = fmaf(xi, wi.w, v[3][j4*4+3]);
        }
    }
    const int rowg = rt * 64 + row;
#pragma unroll
    for (int k = 0; k < 4; ++k) {
        float* o = Vout + (unsigned)k * 524288u + (hn * ROWS + rowg) * 64 + eq * 16;
#pragma unroll
        for (int j4 = 0; j4 < 4; ++j4)
            ((float4*)o)[j4] = make_float4(v[k][j4*4+0], v[k][j4*4+1], v[k][j4*4+2], v[k][j4*4+3]);
    }
    if (t < 64) {
        const int rw = t;
        float cr = 0.f, ci = 0.f;
        for (int d = 0; d < 64; ++d) {
            float br = Abr[h * 64 + d], bi = Abi[h * 64 + d];
            float bm = br - bi, bp = br + bi;
            float xr = sX[0][SXI(d, rw)], xi = sX[1][SXI(d, rw)];
            cr = fmaf(bm, xr, fmaf(-bp, xi, cr));
            ci = fmaf(bm, xi, fmaf( bp, xr, ci));
        }
        cR[hn * ROWS + rt * 64 + rw] = cr;
        cI[hn * ROWS + rt * 64 + rw] = ci;
    }
}

// ---------------------------------------------------------------------------
// K4: AC scores, instnorm applied while staging.
// grid (8 = qt(4)+4*ph(2), 16 hn, 4 b), block 256
// ---------------------------------------------------------------------------
__global__ __launch_bounds__(256) void k_ac(
    const float* __restrict__ wqr, const float* __restrict__ wqi,
    const float* __restrict__ wkr, const float* __restrict__ wki,
    const float* __restrict__ mu,  const float* __restrict__ rs,
    const float* __restrict__ gwr, const float* __restrict__ btwr,
    const float* __restrict__ gwi, const float* __restrict__ btwi,
    float* __restrict__ ACr, float* __restrict__ ACi)
{
    __shared__ float sK[2][64][65];
    __shared__ float sQT[2][64][36];
    const int t = threadIdx.x;
    const int bx = blockIdx.x, qt = bx & 3, ph = bx >> 2;
    const int hn = blockIdx.y, h = hn >> 1;
    const int b = blockIdx.z;
    const float* mu2 = mu + (32 + hn) * 64; const float* rs2 = rs + (32 + hn) * 64;
    const float* mu3 = mu + (48 + hn) * 64; const float* rs3 = rs + (48 + hn) * 64;
#pragma unroll
    for (int j = 0; j < 4; ++j) {
        int flat4 = t + 256 * j;
        int word = flat4 * 4;
        int pp = word >> 6, ee = word & 63;
        int gidx = (hn * ROWS + (ph * 64 + pp) * 4 + b) * 64 + ee;
        float4 kr = *(const float4*)&wkr[gidx];
        float4 ki = *(const float4*)&wki[gidx];
        float4 m2 = *(const float4*)&mu2[ee]; float4 r2 = *(const float4*)&rs2[ee];
        float4 m3 = *(const float4*)&mu3[ee]; float4 r3 = *(const float4*)&rs3[ee];
        sK[0][pp][ee+0] = (kr.x - m2.x) * r2.x; sK[0][pp][ee+1] = (kr.y - m2.y) * r2.y;
        sK[0][pp][ee+2] = (kr.z - m2.z) * r2.z; sK[0][pp][ee+3] = (kr.w - m2.w) * r2.w;
        sK[1][pp][ee+0] = (ki.x - m3.x) * r3.x; sK[1][pp][ee+1] = (ki.y - m3.y) * r3.y;
        sK[1][pp][ee+2] = (ki.z - m3.z) * r3.z; sK[1][pp][ee+3] = (ki.w - m3.w) * r3.w;
    }
    const float* mu0 = mu + hn * 64;        const float* rs0 = rs + hn * 64;
    const float* mu1 = mu + (16 + hn) * 64; const float* rs1 = rs + (16 + hn) * 64;
#pragma unroll
    for (int j = 0; j < 2; ++j) {
        int flat4 = t + 256 * j;
        int word = flat4 * 4;
        int qq = word >> 6, dd = word & 63;
        int gidx = (hn * ROWS + (qt * 32 + qq) * 4 + b) * 64 + dd;
        float4 xr = *(const float4*)&wqr[gidx];
        float4 xi = *(const float4*)&wqi[gidx];
        float4 m0 = *(const float4*)&mu0[dd]; float4 r0 = *(const float4*)&rs0[dd];
        float4 m1 = *(const float4*)&mu1[dd]; float4 r1 = *(const float4*)&rs1[dd];
        float4 g0 = *(const float4*)&gwr[h * 64 + dd]; float4 b0 = *(const float4*)&btwr[h * 64 + dd];
        float4 g1 = *(const float4*)&gwi[h * 64 + dd]; float4 b1 = *(const float4*)&btwi[h * 64 + dd];
        sQT[0][dd+0][qq] = fmaf((xr.x - m0.x) * r0.x, g0.x, b0.x);
        sQT[0][dd+1][qq] = fmaf((xr.y - m0.y) * r0.y, g0.y, b0.y);
        sQT[0][dd+2][qq] = fmaf((xr.z - m0.z) * r0.z, g0.z, b0.z);
        sQT[0][dd+3][qq] = fmaf((xr.w - m0.w) * r0.w, g0.w, b0.w);
        sQT[1][dd+0][qq] = fmaf((xi.x - m1.x) * r1.x, g1.x, b1.x);
        sQT[1][dd+1][qq] = fmaf((xi.y - m1.y) * r1.y, g1.y, b1.y);
        sQT[1][dd+2][qq] = fmaf((xi.z - m1.z) * r1.z, g1.z, b1.z);
        sQT[1][dd+3][qq] = fmaf((xi.w - m1.w) * r1.w, g1.w, b1.w);
    }
    __syncthreads();
    const int p = t & 63, qs = t >> 6;
    float acr[8], aci[8];
#pragma unroll
    for (int j = 0; j < 8; ++j) { acr[j] = 0.f; aci[j] = 0.f; }
    for (int e = 0; e < 64; ++e) {
        float kr = sK[0][p][e], ki = sK[1][p][e];
#pragma unroll
        for (int j4 = 0; j4 < 2; ++j4) {
            float4 qr = *(const float4*)&sQT[0][e][qs * 8 + j4 * 4];
            float4 qi = *(const float4*)&sQT[1][e][qs * 8 + j4 * 4];
            acr[j4*4+0] = fmaf(kr, qr.x, fmaf(-ki, qi.x, acr[j4*4+0]));
            acr[j4*4+1] = fmaf(kr, qr.y, fmaf(-ki, qi.y, acr[j4*4+1]));
            acr[j4*4+2] = fmaf(kr, qr.z, fmaf(-ki, qi.z, acr[j4*4+2]));
            acr[j4*4+3] = fmaf(kr, qr.w, fmaf(-ki, qi.w, acr[j4*4+3]));
            aci[j4*4+0] = fmaf(kr, qi.x, fmaf( ki, qr.x, aci[j4*4+0]));
            aci[j4*4+1] = fmaf(kr, qi.y, fmaf( ki, qr.y, aci[j4*4+1]));
            aci[j4*4+2] = fmaf(kr, qi.z, fmaf( ki, qr.z, aci[j4*4+2]));
            aci[j4*4+3] = fmaf(kr, qi.w, fmaf( ki, qr.w, aci[j4*4+3]));
        }
    }
#pragma unroll
    for (int j = 0; j < 8; ++j) {
        int q = qt * 32 + qs * 8 + j;
        int oidx = ((hn * 128 + q) * 4 + b) * 128 + ph * 64 + p;
        ACr[oidx] = acr[j];
        ACi[oidx] = aci[j];
    }
}

// ---------------------------------------------------------------------------
// K5: fused BD + AC combine + sqrt-affinity + softmax over b.
// Burst-load 128B (one full line) per stream per half -> single fetch/line.
// grid (2 phalf, 256 nq), block 256 (thread: b = t&3, p = ph*64 + t>>2)
// ---------------------------------------------------------------------------
__global__ __launch_bounds__(256) void k_bd(
    const float* __restrict__ ER, const float* __restrict__ EI,
    const float* __restrict__ Vv, const float* __restrict__ cR, const float* __restrict__ cI,
    const float* __restrict__ ACr, const float* __restrict__ ACi,
    float* __restrict__ AFF)
{
    __shared__ float sV[8 * 4 * 260];   // per (h,b): v1|v2|v3|v4 (4*64) + pad 4
    __shared__ float sC[8][4][2];
    const int t = threadIdx.x;
    const int ph = blockIdx.x;
    const int nq = blockIdx.y;
    const int n = nq >> 7, q = nq & 127;
#pragma unroll
    for (int j = 0; j < 8; ++j) {
        int flat4 = t + 256 * j;
        int word = flat4 * 4;
        int e = word & 63, k = (word >> 6) & 3, bb = (word >> 8) & 3, h = word >> 10;
        float4 x = *(const float4*)&Vv[(unsigned)k * 524288u + ((h * 2 + n) * ROWS + q * 4 + bb) * 64 + e];
        *(float4*)&sV[(h * 4 + bb) * 260 + k * 64 + e] = x;
    }
    if (t < 64) {
        int h = t >> 3, bb = (t >> 1) & 3, ri = t & 1;
        const float* c = ri ? cI : cR;
        sC[h][bb][ri] = c[(h * 2 + n) * ROWS + q * 4 + bb];
    }
    const int b = t & 3, p = ph * 64 + (t >> 2);
    const int obase = ((n * 128 + q) * 4 + b) * 128 + p;     // + h*131072
    float ar[8], ai[8];
#pragma unroll
    for (int h = 0; h < 8; ++h) {
        ar[h] = ACr[obase + h * 131072];
        ai[h] = ACi[obase + h * 131072];
    }
    const float4* eqp_r = (const float4*)(ER + (((n * 128 + q) * 128 + p) * 4 + b) * 64);
    const float4* eqp_i = (const float4*)(EI + (((n * 128 + q) * 128 + p) * 4 + b) * 64);
    const float4* epq_r = (const float4*)(ER + (((n * 128 + p) * 128 + q) * 4 + b) * 64);
    const float4* epq_i = (const float4*)(EI + (((n * 128 + p) * 128 + q) * 4 + b) * 64);
    float bdr[8], bdi[8];
#pragma unroll
    for (int h = 0; h < 8; ++h) { bdr[h] = 0.f; bdi[h] = 0.f; }
    __syncthreads();
#pragma unroll 1
    for (int half = 0; half < 2; ++half) {
        float4 A[8], Bv[8], C4[8], D4[8];
#pragma unroll
        for (int j = 0; j < 8; ++j) A[j]  = eqp_r[half * 8 + j];
#pragma unroll
        for (int j = 0; j < 8; ++j) Bv[j] = eqp_i[half * 8 + j];
#pragma unroll
        for (int j = 0; j < 8; ++j) C4[j] = epq_r[half * 8 + j];
#pragma unroll
        for (int j = 0; j < 8; ++j) D4[j] = epq_i[half * 8 + j];
#pragma unroll
        for (int h = 0; h < 8; ++h) {
            const float* base = &sV[(h * 4 + b) * 260 + half * 32];
#pragma unroll
            for (int j = 0; j < 8; ++j) {
                float4 v1 = *(const float4*)(base + j * 4);
                float4 v2 = *(const float4*)(base + 64 + j * 4);
                float4 v3 = *(const float4*)(base + 128 + j * 4);
                float4 v4 = *(const float4*)(base + 192 + j * 4);
                DOT4 (bdr[h], A[j],  v1);
                NDOT4(bdr[h], Bv[j], v2);
                NDOT4(bdr[h], C4[j], v4);
                NDOT4(bdr[h], D4[j], v3);
                DOT4 (bdi[h], A[j],  v3);
                NDOT4(bdi[h], Bv[j], v4);
                DOT4 (bdi[h], C4[j], v2);
                DOT4 (bdi[h], D4[j], v1);
            }
        }
    }
#pragma unroll
    for (int h = 0; h < 8; ++h) {
        float r  = bdr[h] + sC[h][b][0];
        float im = bdi[h] + sC[h][b][1];
        float aff = sqrtf(fmaf(ar[h], ar[h], ai[h] * ai[h])) + sqrtf(fmaf(r, r, im * im));
        float logit = aff * TEMPER;
        float m = fmaxf(logit, __shfl_xor(logit, 1));
        m = fmaxf(m, __shfl_xor(m, 2));
        float ex = __expf(logit - m);
        float s = ex + __shfl_xor(ex, 1);
        s = s + __shfl_xor(s, 2);
        AFF[obase + h * 131072] = ex / s;
    }
}

// ---------------------------------------------------------------------------
// K6: PV contraction over p; writes final concatenated outputs.
// grid 1024 (= N*Q*B), block 512 (thread: h = t>>6, d = t&63)
// ---------------------------------------------------------------------------
__global__ __launch_bounds__(512) void k_pv(
    const float* __restrict__ AFF,
    const float* __restrict__ Vr, const float* __restrict__ Vi,
    float* __restrict__ out)
{
    __shared__ float sA[8][128];
    const int t = threadIdx.x;
    const int nqb = blockIdx.x;
    const int b = nqb & 3, q = (nqb >> 2) & 127, n = nqb >> 9;
#pragma unroll
    for (int j = 0; j < 2; ++j) {
        int flat = t + 512 * j;
        int hh = flat >> 7, p = flat & 127;
        sA[hh][p] = AFF[(((hh * 2 + n) * 128 + q) * 4 + b) * 128 + p];
    }
    __syncthreads();
    const int h = t >> 6, d = t & 63;
    const float* vr = Vr + (n * 128 * 4 + b) * 64 + d;
    const float* vi = Vi + (n * 128 * 4 + b) * 64 + d;
    float o_r = 0.f, o_i = 0.f;
#pragma unroll 4
    for (int p = 0; p < 128; ++p) {
        float a = sA[h][p];
        o_r = fmaf(a, vr[p * 256], o_r);
        o_i = fmaf(a, vi[p * 256], o_i);
    }
    int oidx = ((n * 128 + q) * 4 + b) * 512 + h * 64 + d;
    out[oidx] = o_r;
    out[524288 + oidx] = o_i;
}

// ---------------------------------------------------------------------------
extern "C" void kernel_launch(void* const* d_in, const int* in_sizes, int n_in,
                              void* d_out, int out_size, void* d_ws, size_t ws_size,
                              hipStream_t stream) {
    (void)in_sizes; (void)n_in; (void)out_size; (void)ws_size;
    const float* q_r  = (const float*)d_in[0];
    const float* q_i  = (const float*)d_in[1];
    const float* k_r  = (const float*)d_in[2];
    const float* k_i  = (const float*)d_in[3];
    const float* v_r  = (const float*)d_in[4];
    const float* v_i  = (const float*)d_in[5];
    const float* e_r  = (const float*)d_in[6];
    const float* e_i  = (const float*)d_in[7];
    const float* WKr_w  = (const float*)d_in[8];
    const float* WKi_w  = (const float*)d_in[10];
    const float* WKRr_w = (const float*)d_in[12];
    const float* WKRr_b = (const float*)d_in[13];
    const float* WKRi_w = (const float*)d_in[14];
    const float* WKRi_b = (const float*)d_in[15];
    const float* WQr_w  = (const float*)d_in[16];
    const float* WQi_w  = (const float*)d_in[18];
    const float* ww_r_g  = (const float*)d_in[20];
    const float* ww_r_bt = (const float*)d_in[21];
    const float* ww_i_g  = (const float*)d_in[22];
    const float* ww_i_bt = (const float*)d_in[23];
    const float* wr_r_g  = (const float*)d_in[24];
    const float* wr_r_bt = (const float*)d_in[25];
    const float* wr_i_g  = (const float*)d_in[26];
    const float* wr_i_bt = (const float*)d_in[27];
    float* ws  = (float*)d_ws;
    float* out = (float*)d_out;

    k_proj<<<dim3(8, 16, 2), 256, 0, stream>>>(q_r, q_i, k_r, k_i,
                                               WQr_w, WQi_w, WKr_w, WKi_w, ws);
    k_stats<<<64, 256, 0, stream>>>(ws + WQ_R, ws + MU_, ws + RS_);
    k_vvec<<<dim3(8, 16), 256, 0, stream>>>(ws + WQ_R, ws + WQ_I, ws + MU_, ws + RS_,
                                            WKRr_w, WKRi_w, WKRr_b, WKRi_b,
                                            wr_r_g, wr_r_bt, wr_i_g, wr_i_bt,
                                            ws + VV_, ws + C_R_, ws + C_I_);
    k_ac<<<dim3(8, 16, 4), 256, 0, stream>>>(ws + WQ_R, ws + WQ_I, ws + WK_R, ws + WK_I,
                                             ws + MU_, ws + RS_,
                                             ww_r_g, ww_r_bt, ww_i_g, ww_i_bt,
                                             ws + ACR_, ws + ACI_);
    k_bd<<<dim3(2, 256), 256, 0, stream>>>(e_r, e_i, ws + VV_, ws + C_R_, ws + C_I_,
                                           ws + ACR_, ws + ACI_, ws + AFF_);
    k_pv<<<1024, 512, 0, stream>>>(ws + AFF_, v_r, v_i, out);
}

// Round 3
// 281.837 us; speedup vs baseline: 1.3394x; 1.0322x over previous
//
#include <hip/hip_runtime.h>
#include <math.h>

// Problem constants
#define NH 8
#define DDIM 64
#define NN 2
#define QQ 128
#define PPDIM 128
#define BBD 4
#define ROWS 512           // Q*B == P*B
#define EPSN 1e-5f
#define TEMPER 30.0f

// Workspace layout (float offsets)
#define WQ_R 0u            // [H][N][512][64] rows = q*4+b
#define WQ_I 524288u
#define WK_R 1048576u      // rows = p*4+b
#define WK_I 1572864u
#define MU_  2097152u      // [4][16][64]  tensor: 0 wq_r,1 wq_i,2 wk_r,3 wk_i
#define RS_  2101248u
#define VV_  2105344u      // 4 x [H][N][512][64]  (v1,v2,v3,v4)
#define C_R_ 4202496u      // [H][N][512]
#define C_I_ 4210688u
#define ACR_ 4218880u      // [H][N][Q][B][P]
#define ACI_ 5267456u
#define AFF_ 6316032u      // [H][N][Q][B][P]

#define DOT4(acc, s, v)  { acc = fmaf((s).x,(v).x,acc); acc = fmaf((s).y,(v).y,acc); acc = fmaf((s).z,(v).z,acc); acc = fmaf((s).w,(v).w,acc); }
#define NDOT4(acc, s, v) { acc = fmaf(-(s).x,(v).x,acc); acc = fmaf(-(s).y,(v).y,acc); acc = fmaf(-(s).z,(v).z,acc); acc = fmaf(-(s).w,(v).w,acc); }

// ---------------------------------------------------------------------------
// K1: complex projection (pre-norm), q and k in one launch (grid.z).
// 32 rows per block -> 512 blocks (was 256) for occupancy.
// grid (16 rowtiles, 16 hn, 2 qk), block 256
// ---------------------------------------------------------------------------
__global__ __launch_bounds__(256) void k_proj(
    const float* __restrict__ qR, const float* __restrict__ qI,
    const float* __restrict__ kR, const float* __restrict__ kI,
    const float* __restrict__ WQr, const float* __restrict__ WQi,
    const float* __restrict__ WKr, const float* __restrict__ WKi,
    float* __restrict__ ws)
{
    __shared__ __align__(16) float sWT[2][64 * 64];     // transposed: [e][d]
    const int t  = threadIdx.x;
    const int rt = blockIdx.x;
    const int hn = blockIdx.y;
    const int z  = blockIdx.z;
    const int h = hn >> 1, n = hn & 1;
    const float* inR = z ? kR : qR;
    const float* inI = z ? kI : qI;
    const float* wr0 = (z ? WKr : WQr) + h * 4096;
    const float* wi0 = (z ? WKi : WQi) + h * 4096;
    float* outR = ws + (z ? WK_R : WQ_R);
    float* outI = ws + (z ? WK_I : WQ_I);
#pragma unroll
    for (int j = 0; j < 16; ++j) {
        int flat = t + 256 * j;
        int d = flat & 63, e = flat >> 6;
        sWT[0][e * 64 + d] = wr0[d * 64 + e];
        sWT[1][e * 64 + d] = wi0[d * 64 + e];
    }
    __syncthreads();
    const int row = t & 31, dq = t >> 5;     // dq 0..7, 8 outputs/thread
    const int rowg = rt * 32 + row;
    const float4* xr4 = (const float4*)(inR + (n * ROWS + rowg) * 64);
    const float4* xi4 = (const float4*)(inI + (n * ROWS + rowg) * 64);
    float ar[8], ai[8];
#pragma unroll
    for (int j = 0; j < 8; ++j) { ar[j] = 0.f; ai[j] = 0.f; }
    for (int ec = 0; ec < 16; ++ec) {
        float4 xrv = xr4[ec], xiv = xi4[ec];
        float xrs[4] = {xrv.x, xrv.y, xrv.z, xrv.w};
        float xis[4] = {xiv.x, xiv.y, xiv.z, xiv.w};
#pragma unroll
        for (int u = 0; u < 4; ++u) {
            int e = ec * 4 + u;
            const float4* wrp = (const float4*)&sWT[0][e * 64 + dq * 8];
            const float4* wip = (const float4*)&sWT[1][e * 64 + dq * 8];
            float xr = xrs[u], xi = xis[u];
#pragma unroll
            for (int j4 = 0; j4 < 2; ++j4) {
                float4 wr = wrp[j4], wi = wip[j4];
                ar[j4*4+0] = fmaf(xr, wr.x, fmaf(-xi, wi.x, ar[j4*4+0]));
                ar[j4*4+1] = fmaf(xr, wr.y, fmaf(-xi, wi.y, ar[j4*4+1]));
                ar[j4*4+2] = fmaf(xr, wr.z, fmaf(-xi, wi.z, ar[j4*4+2]));
                ar[j4*4+3] = fmaf(xr, wr.w, fmaf(-xi, wi.w, ar[j4*4+3]));
                ai[j4*4+0] = fmaf(xr, wi.x, fmaf( xi, wr.x, ai[j4*4+0]));
                ai[j4*4+1] = fmaf(xr, wi.y, fmaf( xi, wr.y, ai[j4*4+1]));
                ai[j4*4+2] = fmaf(xr, wi.z, fmaf( xi, wr.z, ai[j4*4+2]));
                ai[j4*4+3] = fmaf(xr, wi.w, fmaf( xi, wr.w, ai[j4*4+3]));
            }
        }
    }
    float* oR = outR + ((unsigned)hn * ROWS + rowg) * 64 + dq * 8;
    float* oI = outI + ((unsigned)hn * ROWS + rowg) * 64 + dq * 8;
#pragma unroll
    for (int j4 = 0; j4 < 2; ++j4) {
        ((float4*)oR)[j4] = make_float4(ar[j4*4+0], ar[j4*4+1], ar[j4*4+2], ar[j4*4+3]);
        ((float4*)oI)[j4] = make_float4(ai[j4*4+0], ai[j4*4+1], ai[j4*4+2], ai[j4*4+3]);
    }
}

// ---------------------------------------------------------------------------
// K2: InstanceNorm stats per (tensor, h, n, d) over 512 rows.  biased var.
// grid 64, block 512 (8 row-parts, dual accumulators for ILP)
// ---------------------------------------------------------------------------
__global__ __launch_bounds__(512) void k_stats(
    const float* __restrict__ base, float* __restrict__ mu, float* __restrict__ rs)
{
    __shared__ float sS[8][64], sQ[8][64];
    const int bid = blockIdx.x, ti = bid >> 4, hn = bid & 15;
    const float* X = base + (unsigned)ti * 524288u + hn * ROWS * 64;
    const int t = threadIdx.x, d = t & 63, part = t >> 6;   // part 0..7
    float s0 = 0.f, s1 = 0.f, q0 = 0.f, q1 = 0.f;
    for (int r = 0; r < 64; r += 2) {
        float x0 = X[(part * 64 + r) * 64 + d];
        float x1 = X[(part * 64 + r + 1) * 64 + d];
        s0 += x0; q0 = fmaf(x0, x0, q0);
        s1 += x1; q1 = fmaf(x1, x1, q1);
    }
    sS[part][d] = s0 + s1; sQ[part][d] = q0 + q1;
    __syncthreads();
    if (t < 64) {
        float st = 0.f, qt = 0.f;
#pragma unroll
        for (int k = 0; k < 8; ++k) { st += sS[k][t]; qt += sQ[k][t]; }
        float m = st * (1.f / 512.f);
        float var = qt * (1.f / 512.f) - m * m;
        mu[(ti * 16 + hn) * 64 + t] = m;
        rs[(ti * 16 + hn) * 64 + t] = rsqrtf(var + EPSN);
    }
}

// ---------------------------------------------------------------------------
// K3: v-vectors v1..v4 = {WKRr,WKRi}^T {wr_qr, wr_qi}, and bias dot terms.
// Split: 32 rows x e'-half per block -> 512 blocks.
// grid (32 = rt(16) + 16*eh(2), 16 hn), block 256
// ---------------------------------------------------------------------------
__global__ __launch_bounds__(256) void k_vvec(
    const float* __restrict__ wqr, const float* __restrict__ wqi,
    const float* __restrict__ mu,  const float* __restrict__ rs,
    const float* __restrict__ Ar,  const float* __restrict__ Ai,
    const float* __restrict__ Abr, const float* __restrict__ Abi,
    const float* __restrict__ gr,  const float* __restrict__ btr,
    const float* __restrict__ gi,  const float* __restrict__ bti,
    float* __restrict__ Vout, float* __restrict__ cR, float* __restrict__ cI)
{
    __shared__ __align__(16) float sW[2][2048];   // [d 64][e'_half 32]
    __shared__ float sX[2][2048];                 // swizzled [d 64][row 32]
    const int t = threadIdx.x;
    const int bx = blockIdx.x, rt = bx & 15, eh = bx >> 4;
    const int hn = blockIdx.y, h = hn >> 1;
    const float* a0 = Ar + h * 4096;
    const float* a1 = Ai + h * 4096;
#pragma unroll
    for (int j = 0; j < 8; ++j) {
        int flat = t + 256 * j;
        int c = flat & 31, r = flat >> 5;
        sW[0][r * 32 + c] = a0[r * 64 + eh * 32 + c];
        sW[1][r * 32 + c] = a1[r * 64 + eh * 32 + c];
    }
    const float* mu0 = mu + hn * 64;        const float* rs0 = rs + hn * 64;
    const float* mu1 = mu + (16 + hn) * 64; const float* rs1 = rs + (16 + hn) * 64;
    {
        const int d = t & 63;            // consecutive lanes -> consecutive d (coalesced)
        const float m0 = mu0[d], r0 = rs0[d], g0 = gr[h * 64 + d], b0 = btr[h * 64 + d];
        const float m1 = mu1[d], r1 = rs1[d], g1 = gi[h * 64 + d], b1 = bti[h * 64 + d];
#pragma unroll
        for (int j = 0; j < 8; ++j) {
            int row = (t >> 6) + 4 * j;  // 0..31
            int gidx = (hn * ROWS + rt * 32 + row) * 64 + d;
            float xr = wqr[gidx], xi = wqi[gidx];
            sX[0][d * 32 + ((row + d) & 31)] = (xr - m0) * r0 * g0 + b0;
            sX[1][d * 32 + ((row + d) & 31)] = (xi - m1) * r1 * g1 + b1;
        }
    }
    __syncthreads();
    const int row = t & 31, eq = t >> 5;   // eq 0..7 -> 4 outputs each
    float v[4][4];
#pragma unroll
    for (int k = 0; k < 4; ++k)
#pragma unroll
        for (int j = 0; j < 4; ++j) v[k][j] = 0.f;
    for (int d = 0; d < 64; ++d) {
        float xr = sX[0][d * 32 + ((row + d) & 31)];
        float xi = sX[1][d * 32 + ((row + d) & 31)];
        float4 wr = *(const float4*)&sW[0][d * 32 + eq * 4];
        float4 wi = *(const float4*)&sW[1][d * 32 + eq * 4];
        v[0][0] = fmaf(xr, wr.x, v[0][0]); v[0][1] = fmaf(xr, wr.y, v[0][1]);
        v[0][2] = fmaf(xr, wr.z, v[0][2]); v[0][3] = fmaf(xr, wr.w, v[0][3]);
        v[1][0] = fmaf(xr, wi.x, v[1][0]); v[1][1] = fmaf(xr, wi.y, v[1][1]);
        v[1][2] = fmaf(xr, wi.z, v[1][2]); v[1][3] = fmaf(xr, wi.w, v[1][3]);
        v[2][0] = fmaf(xi, wr.x, v[2][0]); v[2][1] = fmaf(xi, wr.y, v[2][1]);
        v[2][2] = fmaf(xi, wr.z, v[2][2]); v[2][3] = fmaf(xi, wr.w, v[2][3]);
        v[3][0] = fmaf(xi, wi.x, v[3][0]); v[3][1] = fmaf(xi, wi.y, v[3][1]);
        v[3][2] = fmaf(xi, wi.z, v[3][2]); v[3][3] = fmaf(xi, wi.w, v[3][3]);
    }
    const int rowg = rt * 32 + row;
#pragma unroll
    for (int k = 0; k < 4; ++k) {
        float* o = Vout + (unsigned)k * 524288u + (hn * ROWS + rowg) * 64 + eh * 32 + eq * 4;
        *(float4*)o = make_float4(v[k][0], v[k][1], v[k][2], v[k][3]);
    }
    if (eh == 0 && t < 32) {
        const int rw = t;
        float cr = 0.f, ci = 0.f;
        for (int d = 0; d < 64; ++d) {
            float br = Abr[h * 64 + d], bi = Abi[h * 64 + d];
            float bm = br - bi, bp = br + bi;
            float xr = sX[0][d * 32 + ((rw + d) & 31)];
            float xi = sX[1][d * 32 + ((rw + d) & 31)];
            cr = fmaf(bm, xr, fmaf(-bp, xi, cr));
            ci = fmaf(bm, xi, fmaf( bp, xr, ci));
        }
        cR[hn * ROWS + rt * 32 + rw] = cr;
        cI[hn * ROWS + rt * 32 + rw] = ci;
    }
}

// ---------------------------------------------------------------------------
// K4: AC scores. q-tile 16 -> 1024 blocks.
// grid (16 = qt(8) + 8*ph(2), 16 hn, 4 b), block 256
// ---------------------------------------------------------------------------
__global__ __launch_bounds__(256) void k_ac(
    const float* __restrict__ wqr, const float* __restrict__ wqi,
    const float* __restrict__ wkr, const float* __restrict__ wki,
    const float* __restrict__ mu,  const float* __restrict__ rs,
    const float* __restrict__ gwr, const float* __restrict__ btwr,
    const float* __restrict__ gwi, const float* __restrict__ btwi,
    float* __restrict__ ACr, float* __restrict__ ACi)
{
    __shared__ float sK[2][64][65];
    __shared__ float sQT[2][64][20];   // [d][16 q + pad]
    const int t = threadIdx.x;
    const int bx = blockIdx.x, qt = bx & 7, ph = bx >> 3;
    const int hn = blockIdx.y, h = hn >> 1;
    const int b = blockIdx.z;
    const float* mu2 = mu + (32 + hn) * 64; const float* rs2 = rs + (32 + hn) * 64;
    const float* mu3 = mu + (48 + hn) * 64; const float* rs3 = rs + (48 + hn) * 64;
#pragma unroll
    for (int j = 0; j < 4; ++j) {
        int flat4 = t + 256 * j;
        int word = flat4 * 4;
        int pp = word >> 6, ee = word & 63;
        int gidx = (hn * ROWS + (ph * 64 + pp) * 4 + b) * 64 + ee;
        float4 kr = *(const float4*)&wkr[gidx];
        float4 ki = *(const float4*)&wki[gidx];
        float4 m2 = *(const float4*)&mu2[ee]; float4 r2 = *(const float4*)&rs2[ee];
        float4 m3 = *(const float4*)&mu3[ee]; float4 r3 = *(const float4*)&rs3[ee];
        sK[0][pp][ee+0] = (kr.x - m2.x) * r2.x; sK[0][pp][ee+1] = (kr.y - m2.y) * r2.y;
        sK[0][pp][ee+2] = (kr.z - m2.z) * r2.z; sK[0][pp][ee+3] = (kr.w - m2.w) * r2.w;
        sK[1][pp][ee+0] = (ki.x - m3.x) * r3.x; sK[1][pp][ee+1] = (ki.y - m3.y) * r3.y;
        sK[1][pp][ee+2] = (ki.z - m3.z) * r3.z; sK[1][pp][ee+3] = (ki.w - m3.w) * r3.w;
    }
    const float* mu0 = mu + hn * 64;        const float* rs0 = rs + hn * 64;
    const float* mu1 = mu + (16 + hn) * 64; const float* rs1 = rs + (16 + hn) * 64;
    {
        int word = t * 4;
        int qq = word >> 6, dd = word & 63;          // qq 0..15
        int gidx = (hn * ROWS + (qt * 16 + qq) * 4 + b) * 64 + dd;
        float4 xr = *(const float4*)&wqr[gidx];
        float4 xi = *(const float4*)&wqi[gidx];
        float4 m0 = *(const float4*)&mu0[dd]; float4 r0 = *(const float4*)&rs0[dd];
        float4 m1 = *(const float4*)&mu1[dd]; float4 r1 = *(const float4*)&rs1[dd];
        float4 g0 = *(const float4*)&gwr[h * 64 + dd]; float4 b0 = *(const float4*)&btwr[h * 64 + dd];
        float4 g1 = *(const float4*)&gwi[h * 64 + dd]; float4 b1 = *(const float4*)&btwi[h * 64 + dd];
        sQT[0][dd+0][qq] = fmaf((xr.x - m0.x) * r0.x, g0.x, b0.x);
        sQT[0][dd+1][qq] = fmaf((xr.y - m0.y) * r0.y, g0.y, b0.y);
        sQT[0][dd+2][qq] = fmaf((xr.z - m0.z) * r0.z, g0.z, b0.z);
        sQT[0][dd+3][qq] = fmaf((xr.w - m0.w) * r0.w, g0.w, b0.w);
        sQT[1][dd+0][qq] = fmaf((xi.x - m1.x) * r1.x, g1.x, b1.x);
        sQT[1][dd+1][qq] = fmaf((xi.y - m1.y) * r1.y, g1.y, b1.y);
        sQT[1][dd+2][qq] = fmaf((xi.z - m1.z) * r1.z, g1.z, b1.z);
        sQT[1][dd+3][qq] = fmaf((xi.w - m1.w) * r1.w, g1.w, b1.w);
    }
    __syncthreads();
    const int p = t & 63, qs = t >> 6;
    float acr[4], aci[4];
#pragma unroll
    for (int j = 0; j < 4; ++j) { acr[j] = 0.f; aci[j] = 0.f; }
    for (int e = 0; e < 64; ++e) {
        float kr = sK[0][p][e], ki = sK[1][p][e];
        float4 qr = *(const float4*)&sQT[0][e][qs * 4];
        float4 qi = *(const float4*)&sQT[1][e][qs * 4];
        acr[0] = fmaf(kr, qr.x, fmaf(-ki, qi.x, acr[0]));
        acr[1] = fmaf(kr, qr.y, fmaf(-ki, qi.y, acr[1]));
        acr[2] = fmaf(kr, qr.z, fmaf(-ki, qi.z, acr[2]));
        acr[3] = fmaf(kr, qr.w, fmaf(-ki, qi.w, acr[3]));
        aci[0] = fmaf(kr, qi.x, fmaf( ki, qr.x, aci[0]));
        aci[1] = fmaf(kr, qi.y, fmaf( ki, qr.y, aci[1]));
        aci[2] = fmaf(kr, qi.z, fmaf( ki, qr.z, aci[2]));
        aci[3] = fmaf(kr, qi.w, fmaf( ki, qr.w, aci[3]));
    }
#pragma unroll
    for (int j = 0; j < 4; ++j) {
        int q = qt * 16 + qs * 4 + j;
        int oidx = ((hn * 128 + q) * 4 + b) * 128 + ph * 64 + p;
        ACr[oidx] = acr[j];
        ACi[oidx] = aci[j];
    }
}

// ---------------------------------------------------------------------------
// K5 v3: fused BD + AC + affinity + softmax.  E-MAJOR lanes: lane=(eo,b),
// wave handles 4 p. All emb loads fully line-coalesced (1 KB/instr).
// Butterfly-reduce over e-lanes (xor 1/2/4/8), softmax over b (xor 16/32).
// grid (8 pq, 256 nq), block 256
// ---------------------------------------------------------------------------
__global__ __launch_bounds__(256) void k_bd(
    const float* __restrict__ ER, const float* __restrict__ EI,
    const float* __restrict__ Vv, const float* __restrict__ cR, const float* __restrict__ cI,
    const float* __restrict__ ACr, const float* __restrict__ ACi,
    float* __restrict__ AFF)
{
    __shared__ __align__(16) float sV[8 * 4 * 260];   // per (h,b): v1|v2|v3|v4 + pad
    __shared__ __align__(16) float sAC[2][8][4][16];
    __shared__ float sC[8][4][2];
    const int t = threadIdx.x;
    const int pq = blockIdx.x;
    const int nq = blockIdx.y;
    const int n = nq >> 7, q = nq & 127;
#pragma unroll
    for (int j = 0; j < 8; ++j) {
        int flat4 = t + 256 * j;
        int word = flat4 * 4;
        int e = word & 63, k = (word >> 6) & 3, bb = (word >> 8) & 3, h = word >> 10;
        float4 x = *(const float4*)&Vv[(unsigned)k * 524288u + ((h * 2 + n) * ROWS + q * 4 + bb) * 64 + e];
        *(float4*)&sV[(h * 4 + bb) * 260 + k * 64 + e] = x;
    }
    {
        int c = t & 3, pair = t >> 2;
        int bb = pair & 3, h = (pair >> 2) & 7, ri = pair >> 5;
        const float* src = ri ? ACi : ACr;
        float4 x = *(const float4*)&src[(((h * 2 + n) * 128 + q) * 4 + bb) * 128 + pq * 16 + c * 4];
        *(float4*)&sAC[ri][h][bb][c * 4] = x;
    }
    if (t < 64) {
        int h = t >> 3, bb = (t >> 1) & 3, ri = t & 1;
        const float* c = ri ? cI : cR;
        sC[h][bb][ri] = c[(h * 2 + n) * ROWS + q * 4 + bb];
    }
    __syncthreads();
    const int w = t >> 6, eo = t & 15, b = (t >> 4) & 3;
    const int p0 = pq * 16 + w * 4;
    // 16 fully-coalesced loads (each wave instr = 1 KB contiguous)
    const float* qpR = ER + (((n * 128 + q) * 128 + p0) * 4 + b) * 64 + eo * 4;
    const float* qpI = EI + (((n * 128 + q) * 128 + p0) * 4 + b) * 64 + eo * 4;
    float4 A[4], Bv[4], C4[4], D4[4];
#pragma unroll
    for (int j = 0; j < 4; ++j) {
        A[j]  = *(const float4*)(qpR + j * 256);
        Bv[j] = *(const float4*)(qpI + j * 256);
    }
#pragma unroll
    for (int j = 0; j < 4; ++j) {
        int off = (((n * 128 + p0 + j) * 128 + q) * 4 + b) * 64 + eo * 4;
        C4[j] = *(const float4*)(ER + off);
        D4[j] = *(const float4*)(EI + off);
    }
    float accr[8][4], acci[8][4];
#pragma unroll
    for (int h = 0; h < 8; ++h)
#pragma unroll
        for (int j = 0; j < 4; ++j) { accr[h][j] = 0.f; acci[h][j] = 0.f; }
#pragma unroll
    for (int h = 0; h < 8; ++h) {
        const float* vb = &sV[(h * 4 + b) * 260 + eo * 4];
        float4 v1 = *(const float4*)(vb);
        float4 v2 = *(const float4*)(vb + 64);
        float4 v3 = *(const float4*)(vb + 128);
        float4 v4 = *(const float4*)(vb + 192);
#pragma unroll
        for (int j = 0; j < 4; ++j) {
            DOT4 (accr[h][j], A[j],  v1);
            NDOT4(accr[h][j], Bv[j], v2);
            NDOT4(accr[h][j], C4[j], v4);
            NDOT4(accr[h][j], D4[j], v3);
            DOT4 (acci[h][j], A[j],  v3);
            NDOT4(acci[h][j], Bv[j], v4);
            DOT4 (acci[h][j], C4[j], v2);
            DOT4 (acci[h][j], D4[j], v1);
        }
    }
#pragma unroll
    for (int j = 0; j < 4; ++j) {
        const int pl = w * 4 + j;
#pragma unroll
        for (int h = 0; h < 8; ++h) {
            float rr = accr[h][j], ii = acci[h][j];
            rr += __shfl_xor(rr, 1); rr += __shfl_xor(rr, 2);
            rr += __shfl_xor(rr, 4); rr += __shfl_xor(rr, 8);
            ii += __shfl_xor(ii, 1); ii += __shfl_xor(ii, 2);
            ii += __shfl_xor(ii, 4); ii += __shfl_xor(ii, 8);
            rr += sC[h][b][0]; ii += sC[h][b][1];
            float ar = sAC[0][h][b][pl], ai = sAC[1][h][b][pl];
            float aff = sqrtf(fmaf(ar, ar, ai * ai)) + sqrtf(fmaf(rr, rr, ii * ii));
            float logit = aff * TEMPER;
            float m = fmaxf(logit, __shfl_xor(logit, 16));
            m = fmaxf(m, __shfl_xor(m, 32));
            float ex = __expf(logit - m);
            float s = ex + __shfl_xor(ex, 16);
            s += __shfl_xor(s, 32);
            float val = ex / s;
            if (eo == h)
                AFF[(((h * 2 + n) * 128 + q) * 4 + b) * 128 + pq * 16 + pl] = val;
        }
    }
}

// ---------------------------------------------------------------------------
// K6: PV contraction over p (dual accumulators for ILP).
// grid 1024 (= N*Q*B), block 512 (thread: h = t>>6, d = t&63)
// ---------------------------------------------------------------------------
__global__ __launch_bounds__(512) void k_pv(
    const float* __restrict__ AFF,
    const float* __restrict__ Vr, const float* __restrict__ Vi,
    float* __restrict__ out)
{
    __shared__ float sA[8][128];
    const int t = threadIdx.x;
    const int nqb = blockIdx.x;
    const int b = nqb & 3, q = (nqb >> 2) & 127, n = nqb >> 9;
#pragma unroll
    for (int j = 0; j < 2; ++j) {
        int flat = t + 512 * j;
        int hh = flat >> 7, p = flat & 127;
        sA[hh][p] = AFF[(((hh * 2 + n) * 128 + q) * 4 + b) * 128 + p];
    }
    __syncthreads();
    const int h = t >> 6, d = t & 63;
    const float* vr = Vr + (n * 128 * 4 + b) * 64 + d;
    const float* vi = Vi + (n * 128 * 4 + b) * 64 + d;
    float or0 = 0.f, or1 = 0.f, oi0 = 0.f, oi1 = 0.f;
#pragma unroll 4
    for (int p = 0; p < 128; p += 2) {
        float a0 = sA[h][p], a1 = sA[h][p + 1];
        or0 = fmaf(a0, vr[p * 256], or0);
        oi0 = fmaf(a0, vi[p * 256], oi0);
        or1 = fmaf(a1, vr[(p + 1) * 256], or1);
        oi1 = fmaf(a1, vi[(p + 1) * 256], oi1);
    }
    int oidx = ((n * 128 + q) * 4 + b) * 512 + h * 64 + d;
    out[oidx] = or0 + or1;
    out[524288 + oidx] = oi0 + oi1;
}

// ---------------------------------------------------------------------------
extern "C" void kernel_launch(void* const* d_in, const int* in_sizes, int n_in,
                              void* d_out, int out_size, void* d_ws, size_t ws_size,
                              hipStream_t stream) {
    (void)in_sizes; (void)n_in; (void)out_size; (void)ws_size;
    const float* q_r  = (const float*)d_in[0];
    const float* q_i  = (const float*)d_in[1];
    const float* k_r  = (const float*)d_in[2];
    const float* k_i  = (const float*)d_in[3];
    const float* v_r  = (const float*)d_in[4];
    const float* v_i  = (const float*)d_in[5];
    const float* e_r  = (const float*)d_in[6];
    const float* e_i  = (const float*)d_in[7];
    const float* WKr_w  = (const float*)d_in[8];
    const float* WKi_w  = (const float*)d_in[10];
    const float* WKRr_w = (const float*)d_in[12];
    const float* WKRr_b = (const float*)d_in[13];
    const float* WKRi_w = (const float*)d_in[14];
    const float* WKRi_b = (const float*)d_in[15];
    const float* WQr_w  = (const float*)d_in[16];
    const float* WQi_w  = (const float*)d_in[18];
    const float* ww_r_g  = (const float*)d_in[20];
    const float* ww_r_bt = (const float*)d_in[21];
    const float* ww_i_g  = (const float*)d_in[22];
    const float* ww_i_bt = (const float*)d_in[23];
    const float* wr_r_g  = (const float*)d_in[24];
    const float* wr_r_bt = (const float*)d_in[25];
    const float* wr_i_g  = (const float*)d_in[26];
    const float* wr_i_bt = (const float*)d_in[27];
    float* ws  = (float*)d_ws;
    float* out = (float*)d_out;

    k_proj<<<dim3(16, 16, 2), 256, 0, stream>>>(q_r, q_i, k_r, k_i,
                                                WQr_w, WQi_w, WKr_w, WKi_w, ws);
    k_stats<<<64, 512, 0, stream>>>(ws + WQ_R, ws + MU_, ws + RS_);
    k_vvec<<<dim3(32, 16), 256, 0, stream>>>(ws + WQ_R, ws + WQ_I, ws + MU_, ws + RS_,
                                             WKRr_w, WKRi_w, WKRr_b, WKRi_b,
                                             wr_r_g, wr_r_bt, wr_i_g, wr_i_bt,
                                             ws + VV_, ws + C_R_, ws + C_I_);
    k_ac<<<dim3(16, 16, 4), 256, 0, stream>>>(ws + WQ_R, ws + WQ_I, ws + WK_R, ws + WK_I,
                                              ws + MU_, ws + RS_,
                                              ww_r_g, ww_r_bt, ww_i_g, ww_i_bt,
                                              ws + ACR_, ws + ACI_);
    k_bd<<<dim3(8, 256), 256, 0, stream>>>(e_r, e_i, ws + VV_, ws + C_R_, ws + C_I_,
                                           ws + ACR_, ws + ACI_, ws + AFF_);
    k_pv<<<1024, 512, 0, stream>>>(ws + AFF_, v_r, v_i, out);
}

// Round 4
// 275.060 us; speedup vs baseline: 1.3724x; 1.0246x over previous
//
#include <hip/hip_runtime.h>
#include <math.h>

// Problem constants
#define NH 8
#define DDIM 64
#define NN 2
#define QQ 128
#define PPDIM 128
#define BBD 4
#define ROWS 512           // Q*B == P*B
#define EPSN 1e-5f
#define TEMPER 30.0f

// Workspace layout (float offsets)
#define WQ_R 0u            // [H][N][512][64] rows = q*4+b
#define WQ_I 524288u
#define WK_R 1048576u      // rows = p*4+b
#define WK_I 1572864u
#define MU_  2097152u      // [4][16][64]  tensor: 0 wq_r,1 wq_i,2 wk_r,3 wk_i
#define RS_  2101248u
#define VV_  2105344u      // 4 x [H][N][512][64]  (v1,v2,v3,v4)
#define C_R_ 4202496u      // [H][N][512]
#define C_I_ 4210688u
#define ACR_ 4218880u      // [H][N][Q][B][P]   (also reused as stats scratch early)
#define ACI_ 5267456u
#define AFF_ 6316032u      // [N][Q][B][H][P]
#define PART_ ACR_         // stats partials: [256 blk][2][64]  (free until k_ac)

#define DOT4(acc, s, v)  { acc = fmaf((s).x,(v).x,acc); acc = fmaf((s).y,(v).y,acc); acc = fmaf((s).z,(v).z,acc); acc = fmaf((s).w,(v).w,acc); }
#define NDOT4(acc, s, v) { acc = fmaf(-(s).x,(v).x,acc); acc = fmaf(-(s).y,(v).y,acc); acc = fmaf(-(s).z,(v).z,acc); acc = fmaf(-(s).w,(v).w,acc); }

// ---------------------------------------------------------------------------
// K1: complex projection (pre-norm), q and k in one launch (grid.z).
// grid (16 rowtiles, 16 hn, 2 qk), block 256
// ---------------------------------------------------------------------------
__global__ __launch_bounds__(256) void k_proj(
    const float* __restrict__ qR, const float* __restrict__ qI,
    const float* __restrict__ kR, const float* __restrict__ kI,
    const float* __restrict__ WQr, const float* __restrict__ WQi,
    const float* __restrict__ WKr, const float* __restrict__ WKi,
    float* __restrict__ ws)
{
    __shared__ __align__(16) float sWT[2][64 * 64];     // transposed: [e][d]
    const int t  = threadIdx.x;
    const int rt = blockIdx.x;
    const int hn = blockIdx.y;
    const int z  = blockIdx.z;
    const int h = hn >> 1, n = hn & 1;
    const float* inR = z ? kR : qR;
    const float* inI = z ? kI : qI;
    const float* wr0 = (z ? WKr : WQr) + h * 4096;
    const float* wi0 = (z ? WKi : WQi) + h * 4096;
    float* outR = ws + (z ? WK_R : WQ_R);
    float* outI = ws + (z ? WK_I : WQ_I);
#pragma unroll
    for (int j = 0; j < 16; ++j) {
        int flat = t + 256 * j;
        int d = flat & 63, e = flat >> 6;
        sWT[0][e * 64 + d] = wr0[d * 64 + e];
        sWT[1][e * 64 + d] = wi0[d * 64 + e];
    }
    __syncthreads();
    const int row = t & 31, dq = t >> 5;     // dq 0..7, 8 outputs/thread
    const int rowg = rt * 32 + row;
    const float4* xr4 = (const float4*)(inR + (n * ROWS + rowg) * 64);
    const float4* xi4 = (const float4*)(inI + (n * ROWS + rowg) * 64);
    float ar[8], ai[8];
#pragma unroll
    for (int j = 0; j < 8; ++j) { ar[j] = 0.f; ai[j] = 0.f; }
    for (int ec = 0; ec < 16; ++ec) {
        float4 xrv = xr4[ec], xiv = xi4[ec];
        float xrs[4] = {xrv.x, xrv.y, xrv.z, xrv.w};
        float xis[4] = {xiv.x, xiv.y, xiv.z, xiv.w};
#pragma unroll
        for (int u = 0; u < 4; ++u) {
            int e = ec * 4 + u;
            const float4* wrp = (const float4*)&sWT[0][e * 64 + dq * 8];
            const float4* wip = (const float4*)&sWT[1][e * 64 + dq * 8];
            float xr = xrs[u], xi = xis[u];
#pragma unroll
            for (int j4 = 0; j4 < 2; ++j4) {
                float4 wr = wrp[j4], wi = wip[j4];
                ar[j4*4+0] = fmaf(xr, wr.x, fmaf(-xi, wi.x, ar[j4*4+0]));
                ar[j4*4+1] = fmaf(xr, wr.y, fmaf(-xi, wi.y, ar[j4*4+1]));
                ar[j4*4+2] = fmaf(xr, wr.z, fmaf(-xi, wi.z, ar[j4*4+2]));
                ar[j4*4+3] = fmaf(xr, wr.w, fmaf(-xi, wi.w, ar[j4*4+3]));
                ai[j4*4+0] = fmaf(xr, wi.x, fmaf( xi, wr.x, ai[j4*4+0]));
                ai[j4*4+1] = fmaf(xr, wi.y, fmaf( xi, wr.y, ai[j4*4+1]));
                ai[j4*4+2] = fmaf(xr, wi.z, fmaf( xi, wr.z, ai[j4*4+2]));
                ai[j4*4+3] = fmaf(xr, wi.w, fmaf( xi, wr.w, ai[j4*4+3]));
            }
        }
    }
    float* oR = outR + ((unsigned)hn * ROWS + rowg) * 64 + dq * 8;
    float* oI = outI + ((unsigned)hn * ROWS + rowg) * 64 + dq * 8;
#pragma unroll
    for (int j4 = 0; j4 < 2; ++j4) {
        ((float4*)oR)[j4] = make_float4(ar[j4*4+0], ar[j4*4+1], ar[j4*4+2], ar[j4*4+3]);
        ((float4*)oI)[j4] = make_float4(ai[j4*4+0], ai[j4*4+1], ai[j4*4+2], ai[j4*4+3]);
    }
}

// ---------------------------------------------------------------------------
// K2a: InstanceNorm partial sums.  grid 256 (= 64 groups * 4 row-chunks), block 256.
// part layout: [bid][2][64]  (s then sq)
// ---------------------------------------------------------------------------
__global__ __launch_bounds__(256) void k_stats1(
    const float* __restrict__ base, float* __restrict__ part)
{
    __shared__ float sS[4][64], sQ[4][64];
    const int bid = blockIdx.x;
    const int grp = bid >> 2, cc = bid & 3;
    const int ti = grp >> 4, hn = grp & 15;
    const float* X = base + (unsigned)ti * 524288u + hn * ROWS * 64 + cc * 128 * 64;
    const int t = threadIdx.x, d = t & 63, pt = t >> 6;
    float s0 = 0.f, s1 = 0.f, q0 = 0.f, q1 = 0.f;
    for (int r = 0; r < 32; r += 2) {
        float x0 = X[(pt * 32 + r) * 64 + d];
        float x1 = X[(pt * 32 + r + 1) * 64 + d];
        s0 += x0; q0 = fmaf(x0, x0, q0);
        s1 += x1; q1 = fmaf(x1, x1, q1);
    }
    sS[pt][d] = s0 + s1; sQ[pt][d] = q0 + q1;
    __syncthreads();
    if (t < 64) {
        part[bid * 128 + t]      = sS[0][t] + sS[1][t] + sS[2][t] + sS[3][t];
        part[bid * 128 + 64 + t] = sQ[0][t] + sQ[1][t] + sQ[2][t] + sQ[3][t];
    }
}

// K2b: finalize stats.  grid 64 (= groups), block 64.
__global__ __launch_bounds__(64) void k_stats2(
    const float* __restrict__ part, float* __restrict__ mu, float* __restrict__ rs)
{
    const int grp = blockIdx.x, d = threadIdx.x;
    float s = 0.f, q = 0.f;
#pragma unroll
    for (int cc = 0; cc < 4; ++cc) {
        s += part[(grp * 4 + cc) * 128 + d];
        q += part[(grp * 4 + cc) * 128 + 64 + d];
    }
    float m = s * (1.f / 512.f);
    float var = q * (1.f / 512.f) - m * m;
    mu[grp * 64 + d] = m;
    rs[grp * 64 + d] = rsqrtf(var + EPSN);
}

// ---------------------------------------------------------------------------
// K3: v-vectors v1..v4 = {WKRr,WKRi}^T {wr_qr, wr_qi}, and bias dot terms.
// grid (32 = rt(16) + 16*eh(2), 16 hn), block 256
// ---------------------------------------------------------------------------
__global__ __launch_bounds__(256) void k_vvec(
    const float* __restrict__ wqr, const float* __restrict__ wqi,
    const float* __restrict__ mu,  const float* __restrict__ rs,
    const float* __restrict__ Ar,  const float* __restrict__ Ai,
    const float* __restrict__ Abr, const float* __restrict__ Abi,
    const float* __restrict__ gr,  const float* __restrict__ btr,
    const float* __restrict__ gi,  const float* __restrict__ bti,
    float* __restrict__ Vout, float* __restrict__ cR, float* __restrict__ cI)
{
    __shared__ __align__(16) float sW[2][2048];   // [d 64][e'_half 32]
    __shared__ float sX[2][2048];                 // swizzled [d 64][row 32]
    const int t = threadIdx.x;
    const int bx = blockIdx.x, rt = bx & 15, eh = bx >> 4;
    const int hn = blockIdx.y, h = hn >> 1;
    const float* a0 = Ar + h * 4096;
    const float* a1 = Ai + h * 4096;
#pragma unroll
    for (int j = 0; j < 8; ++j) {
        int flat = t + 256 * j;
        int c = flat & 31, r = flat >> 5;
        sW[0][r * 32 + c] = a0[r * 64 + eh * 32 + c];
        sW[1][r * 32 + c] = a1[r * 64 + eh * 32 + c];
    }
    const float* mu0 = mu + hn * 64;        const float* rs0 = rs + hn * 64;
    const float* mu1 = mu + (16 + hn) * 64; const float* rs1 = rs + (16 + hn) * 64;
    {
        const int d = t & 63;
        const float m0 = mu0[d], r0 = rs0[d], g0 = gr[h * 64 + d], b0 = btr[h * 64 + d];
        const float m1 = mu1[d], r1 = rs1[d], g1 = gi[h * 64 + d], b1 = bti[h * 64 + d];
#pragma unroll
        for (int j = 0; j < 8; ++j) {
            int row = (t >> 6) + 4 * j;  // 0..31
            int gidx = (hn * ROWS + rt * 32 + row) * 64 + d;
            float xr = wqr[gidx], xi = wqi[gidx];
            sX[0][d * 32 + ((row + d) & 31)] = (xr - m0) * r0 * g0 + b0;
            sX[1][d * 32 + ((row + d) & 31)] = (xi - m1) * r1 * g1 + b1;
        }
    }
    __syncthreads();
    const int row = t & 31, eq = t >> 5;   // eq 0..7 -> 4 outputs each
    float v[4][4];
#pragma unroll
    for (int k = 0; k < 4; ++k)
#pragma unroll
        for (int j = 0; j < 4; ++j) v[k][j] = 0.f;
    for (int d = 0; d < 64; ++d) {
        float xr = sX[0][d * 32 + ((row + d) & 31)];
        float xi = sX[1][d * 32 + ((row + d) & 31)];
        float4 wr = *(const float4*)&sW[0][d * 32 + eq * 4];
        float4 wi = *(const float4*)&sW[1][d * 32 + eq * 4];
        v[0][0] = fmaf(xr, wr.x, v[0][0]); v[0][1] = fmaf(xr, wr.y, v[0][1]);
        v[0][2] = fmaf(xr, wr.z, v[0][2]); v[0][3] = fmaf(xr, wr.w, v[0][3]);
        v[1][0] = fmaf(xr, wi.x, v[1][0]); v[1][1] = fmaf(xr, wi.y, v[1][1]);
        v[1][2] = fmaf(xr, wi.z, v[1][2]); v[1][3] = fmaf(xr, wi.w, v[1][3]);
        v[2][0] = fmaf(xi, wr.x, v[2][0]); v[2][1] = fmaf(xi, wr.y, v[2][1]);
        v[2][2] = fmaf(xi, wr.z, v[2][2]); v[2][3] = fmaf(xi, wr.w, v[2][3]);
        v[3][0] = fmaf(xi, wi.x, v[3][0]); v[3][1] = fmaf(xi, wi.y, v[3][1]);
        v[3][2] = fmaf(xi, wi.z, v[3][2]); v[3][3] = fmaf(xi, wi.w, v[3][3]);
    }
    const int rowg = rt * 32 + row;
#pragma unroll
    for (int k = 0; k < 4; ++k) {
        float* o = Vout + (unsigned)k * 524288u + (hn * ROWS + rowg) * 64 + eh * 32 + eq * 4;
        *(float4*)o = make_float4(v[k][0], v[k][1], v[k][2], v[k][3]);
    }
    if (eh == 0 && t < 32) {
        const int rw = t;
        float cr = 0.f, ci = 0.f;
        for (int d = 0; d < 64; ++d) {
            float br = Abr[h * 64 + d], bi = Abi[h * 64 + d];
            float bm = br - bi, bp = br + bi;
            float xr = sX[0][d * 32 + ((rw + d) & 31)];
            float xi = sX[1][d * 32 + ((rw + d) & 31)];
            cr = fmaf(bm, xr, fmaf(-bp, xi, cr));
            ci = fmaf(bm, xi, fmaf( bp, xr, ci));
        }
        cR[hn * ROWS + rt * 32 + rw] = cr;
        cI[hn * ROWS + rt * 32 + rw] = ci;
    }
}

// ---------------------------------------------------------------------------
// K4: AC scores. grid (16 = qt(8) + 8*ph(2), 16 hn, 4 b), block 256
// ---------------------------------------------------------------------------
__global__ __launch_bounds__(256) void k_ac(
    const float* __restrict__ wqr, const float* __restrict__ wqi,
    const float* __restrict__ wkr, const float* __restrict__ wki,
    const float* __restrict__ mu,  const float* __restrict__ rs,
    const float* __restrict__ gwr, const float* __restrict__ btwr,
    const float* __restrict__ gwi, const float* __restrict__ btwi,
    float* __restrict__ ACr, float* __restrict__ ACi)
{
    __shared__ float sK[2][64][65];
    __shared__ float sQT[2][64][20];   // [d][16 q + pad]
    const int t = threadIdx.x;
    const int bx = blockIdx.x, qt = bx & 7, ph = bx >> 3;
    const int hn = blockIdx.y, h = hn >> 1;
    const int b = blockIdx.z;
    const float* mu2 = mu + (32 + hn) * 64; const float* rs2 = rs + (32 + hn) * 64;
    const float* mu3 = mu + (48 + hn) * 64; const float* rs3 = rs + (48 + hn) * 64;
#pragma unroll
    for (int j = 0; j < 4; ++j) {
        int flat4 = t + 256 * j;
        int word = flat4 * 4;
        int pp = word >> 6, ee = word & 63;
        int gidx = (hn * ROWS + (ph * 64 + pp) * 4 + b) * 64 + ee;
        float4 kr = *(const float4*)&wkr[gidx];
        float4 ki = *(const float4*)&wki[gidx];
        float4 m2 = *(const float4*)&mu2[ee]; float4 r2 = *(const float4*)&rs2[ee];
        float4 m3 = *(const float4*)&mu3[ee]; float4 r3 = *(const float4*)&rs3[ee];
        sK[0][pp][ee+0] = (kr.x - m2.x) * r2.x; sK[0][pp][ee+1] = (kr.y - m2.y) * r2.y;
        sK[0][pp][ee+2] = (kr.z - m2.z) * r2.z; sK[0][pp][ee+3] = (kr.w - m2.w) * r2.w;
        sK[1][pp][ee+0] = (ki.x - m3.x) * r3.x; sK[1][pp][ee+1] = (ki.y - m3.y) * r3.y;
        sK[1][pp][ee+2] = (ki.z - m3.z) * r3.z; sK[1][pp][ee+3] = (ki.w - m3.w) * r3.w;
    }
    const float* mu0 = mu + hn * 64;        const float* rs0 = rs + hn * 64;
    const float* mu1 = mu + (16 + hn) * 64; const float* rs1 = rs + (16 + hn) * 64;
    {
        int word = t * 4;
        int qq = word >> 6, dd = word & 63;          // qq 0..15
        int gidx = (hn * ROWS + (qt * 16 + qq) * 4 + b) * 64 + dd;
        float4 xr = *(const float4*)&wqr[gidx];
        float4 xi = *(const float4*)&wqi[gidx];
        float4 m0 = *(const float4*)&mu0[dd]; float4 r0 = *(const float4*)&rs0[dd];
        float4 m1 = *(const float4*)&mu1[dd]; float4 r1 = *(const float4*)&rs1[dd];
        float4 g0 = *(const float4*)&gwr[h * 64 + dd]; float4 b0 = *(const float4*)&btwr[h * 64 + dd];
        float4 g1 = *(const float4*)&gwi[h * 64 + dd]; float4 b1 = *(const float4*)&btwi[h * 64 + dd];
        sQT[0][dd+0][qq] = fmaf((xr.x - m0.x) * r0.x, g0.x, b0.x);
        sQT[0][dd+1][qq] = fmaf((xr.y - m0.y) * r0.y, g0.y, b0.y);
        sQT[0][dd+2][qq] = fmaf((xr.z - m0.z) * r0.z, g0.z, b0.z);
        sQT[0][dd+3][qq] = fmaf((xr.w - m0.w) * r0.w, g0.w, b0.w);
        sQT[1][dd+0][qq] = fmaf((xi.x - m1.x) * r1.x, g1.x, b1.x);
        sQT[1][dd+1][qq] = fmaf((xi.y - m1.y) * r1.y, g1.y, b1.y);
        sQT[1][dd+2][qq] = fmaf((xi.z - m1.z) * r1.z, g1.z, b1.z);
        sQT[1][dd+3][qq] = fmaf((xi.w - m1.w) * r1.w, g1.w, b1.w);
    }
    __syncthreads();
    const int p = t & 63, qs = t >> 6;
    float acr[4], aci[4];
#pragma unroll
    for (int j = 0; j < 4; ++j) { acr[j] = 0.f; aci[j] = 0.f; }
    for (int e = 0; e < 64; ++e) {
        float kr = sK[0][p][e], ki = sK[1][p][e];
        float4 qr = *(const float4*)&sQT[0][e][qs * 4];
        float4 qi = *(const float4*)&sQT[1][e][qs * 4];
        acr[0] = fmaf(kr, qr.x, fmaf(-ki, qi.x, acr[0]));
        acr[1] = fmaf(kr, qr.y, fmaf(-ki, qi.y, acr[1]));
        acr[2] = fmaf(kr, qr.z, fmaf(-ki, qi.z, acr[2]));
        acr[3] = fmaf(kr, qr.w, fmaf(-ki, qi.w, acr[3]));
        aci[0] = fmaf(kr, qi.x, fmaf( ki, qr.x, aci[0]));
        aci[1] = fmaf(kr, qi.y, fmaf( ki, qr.y, aci[1]));
        aci[2] = fmaf(kr, qi.z, fmaf( ki, qr.z, aci[2]));
        aci[3] = fmaf(kr, qi.w, fmaf( ki, qr.w, aci[3]));
    }
#pragma unroll
    for (int j = 0; j < 4; ++j) {
        int q = qt * 16 + qs * 4 + j;
        int oidx = ((hn * 128 + q) * 4 + b) * 128 + ph * 64 + p;
        ACr[oidx] = acr[j];
        ACi[oidx] = aci[j];
    }
}

// ---------------------------------------------------------------------------
// K5 v4: fused BD + AC + affinity + softmax.  wave = b, lane = (eo 16, pl 4).
// No shuffles: e-reduction via per-wave LDS transpose (stride-17 = 2-way free).
// Softmax over b via tiny LDS roundtrip.  p-tile 16 -> 2048 blocks.
// grid (8 pq, 256 nq), block 256
// ---------------------------------------------------------------------------
__global__ __launch_bounds__(256) void k_bd(
    const float* __restrict__ ER, const float* __restrict__ EI,
    const float* __restrict__ Vv, const float* __restrict__ cR, const float* __restrict__ cI,
    const float* __restrict__ ACr, const float* __restrict__ ACi,
    float* __restrict__ AFF)
{
    __shared__ float sP[4 * 2176];   // per-wave scratch: 128 chains * 17
    __shared__ float sL[128 * 5];    // logits [c][b]
    const int t = threadIdx.x;
    const int w = t >> 6;            // wave = b
    const int l = t & 63;
    const int eo = l & 15, pl = l >> 4;
    const int pq = blockIdx.x;
    const int nq = blockIdx.y;
    const int n = nq >> 7, q = nq & 127;
    const int P0 = pq * 16;

    float accr[8][4], acci[8][4];
#pragma unroll
    for (int h = 0; h < 8; ++h)
#pragma unroll
        for (int j = 0; j < 4; ++j) { accr[h][j] = 0.f; acci[h][j] = 0.f; }

#pragma unroll
    for (int jc = 0; jc < 2; ++jc) {
        float4 A[2], Bv[2], C4[2], D4[2];
#pragma unroll
        for (int jj = 0; jj < 2; ++jj) {
            int j = jc * 2 + jj;
            int p = P0 + pl * 4 + j;
            int qpo = (((n * 128 + q) * 128 + p) * 4 + w) * 64 + eo * 4;
            int pqo = (((n * 128 + p) * 128 + q) * 4 + w) * 64 + eo * 4;
            A[jj]  = *(const float4*)(ER + qpo);
            Bv[jj] = *(const float4*)(EI + qpo);
            C4[jj] = *(const float4*)(ER + pqo);
            D4[jj] = *(const float4*)(EI + pqo);
        }
#pragma unroll
        for (int h = 0; h < 8; ++h) {
            unsigned vb = ((h * 2 + n) * ROWS + q * 4 + w) * 64u + eo * 4;
            float4 v1 = *(const float4*)(Vv + vb);
            float4 v2 = *(const float4*)(Vv + 524288u + vb);
            float4 v3 = *(const float4*)(Vv + 1048576u + vb);
            float4 v4 = *(const float4*)(Vv + 1572864u + vb);
#pragma unroll
            for (int jj = 0; jj < 2; ++jj) {
                int j = jc * 2 + jj;
                DOT4 (accr[h][j], A[jj],  v1);
                NDOT4(accr[h][j], Bv[jj], v2);
                NDOT4(accr[h][j], C4[jj], v4);
                NDOT4(accr[h][j], D4[jj], v3);
                DOT4 (acci[h][j], A[jj],  v3);
                NDOT4(acci[h][j], Bv[jj], v4);
                DOT4 (acci[h][j], C4[jj], v2);
                DOT4 (acci[h][j], D4[jj], v1);
            }
        }
    }

    // Output assignments: lane l handles c1 = l (h 0..3) and c2 = l+64 (h 4..7)
    const int c1 = l, c2 = l + 64;
    const int h1 = c1 >> 4, h2 = h1 + 4;
    const int pc = c1 & 15;                 // same for c2
    const int jr = pc >> 2, plr = pc & 3;
    const int poff = plr * 4 + jr;
    // prefetch AC + c (L2-hot, latency overlaps LDS reduction)
    float ac_r1 = ACr[(((h1 * 2 + n) * 128 + q) * 4 + w) * 128 + P0 + poff];
    float ac_i1 = ACi[(((h1 * 2 + n) * 128 + q) * 4 + w) * 128 + P0 + poff];
    float ac_r2 = ACr[(((h2 * 2 + n) * 128 + q) * 4 + w) * 128 + P0 + poff];
    float ac_i2 = ACi[(((h2 * 2 + n) * 128 + q) * 4 + w) * 128 + P0 + poff];
    float cr1 = cR[(h1 * 2 + n) * ROWS + q * 4 + w];
    float ci1 = cI[(h1 * 2 + n) * ROWS + q * 4 + w];
    float cr2 = cR[(h2 * 2 + n) * ROWS + q * 4 + w];
    float ci2 = cI[(h2 * 2 + n) * ROWS + q * 4 + w];

    float* wb = sP + w * 2176;
    // ---- r pass ----
#pragma unroll
    for (int h = 0; h < 8; ++h)
#pragma unroll
        for (int j = 0; j < 4; ++j)
            wb[(h * 16 + j * 4 + pl) * 17 + eo] = accr[h][j];
    __syncthreads();
    float bdr1 = 0.f, bdr2 = 0.f;
#pragma unroll
    for (int i = 0; i < 16; ++i) {
        bdr1 += wb[c1 * 17 + i];
        bdr2 += wb[c2 * 17 + i];
    }
    __syncthreads();
    // ---- i pass ----
#pragma unroll
    for (int h = 0; h < 8; ++h)
#pragma unroll
        for (int j = 0; j < 4; ++j)
            wb[(h * 16 + j * 4 + pl) * 17 + eo] = acci[h][j];
    __syncthreads();
    float bdi1 = 0.f, bdi2 = 0.f;
#pragma unroll
    for (int i = 0; i < 16; ++i) {
        bdi1 += wb[c1 * 17 + i];
        bdi2 += wb[c2 * 17 + i];
    }

    bdr1 += cr1; bdi1 += ci1;
    bdr2 += cr2; bdi2 += ci2;
    float aff1 = sqrtf(fmaf(ac_r1, ac_r1, ac_i1 * ac_i1)) + sqrtf(fmaf(bdr1, bdr1, bdi1 * bdi1));
    float aff2 = sqrtf(fmaf(ac_r2, ac_r2, ac_i2 * ac_i2)) + sqrtf(fmaf(bdr2, bdr2, bdi2 * bdi2));
    float lg1 = aff1 * TEMPER, lg2 = aff2 * TEMPER;
    sL[c1 * 5 + w] = lg1;
    sL[c2 * 5 + w] = lg2;
    __syncthreads();
    {
        float l0 = sL[c1 * 5 + 0], l1x = sL[c1 * 5 + 1], l2x = sL[c1 * 5 + 2], l3x = sL[c1 * 5 + 3];
        float m = fmaxf(fmaxf(l0, l1x), fmaxf(l2x, l3x));
        float s = __expf(l0 - m) + __expf(l1x - m) + __expf(l2x - m) + __expf(l3x - m);
        AFF[(unsigned)((nq * 4 + w) * 8 + h1) * 128 + P0 + poff] = __expf(lg1 - m) / s;
    }
    {
        float l0 = sL[c2 * 5 + 0], l1x = sL[c2 * 5 + 1], l2x = sL[c2 * 5 + 2], l3x = sL[c2 * 5 + 3];
        float m = fmaxf(fmaxf(l0, l1x), fmaxf(l2x, l3x));
        float s = __expf(l0 - m) + __expf(l1x - m) + __expf(l2x - m) + __expf(l3x - m);
        AFF[(unsigned)((nq * 4 + w) * 8 + h2) * 128 + P0 + poff] = __expf(lg2 - m) / s;
    }
}

// ---------------------------------------------------------------------------
// K6 v2: PV contraction, no redundant V reads. block = (n,q,b), thread=(d,pp).
// AFF layout [n][q][b][h][p] -> 1024 contiguous floats per block.
// grid 1024, block 256
// ---------------------------------------------------------------------------
__global__ __launch_bounds__(256) void k_pv(
    const float* __restrict__ AFF,
    const float* __restrict__ Vr, const float* __restrict__ Vi,
    float* __restrict__ out)
{
    __shared__ float sA[8 * 132];
    __shared__ float sRed[4 * 1092];
    const int t = threadIdx.x;
    const int nqb = blockIdx.x;
    const int b = nqb & 3, q = (nqb >> 2) & 127, n = nqb >> 9;
#pragma unroll
    for (int j = 0; j < 4; ++j) {
        int idx = t + 256 * j;
        sA[(idx >> 7) * 132 + (idx & 127)] = AFF[(unsigned)nqb * 1024u + idx];
    }
    __syncthreads();
    const int d = t & 63, pp = t >> 6;
    const float* vr = Vr + (n * 512 + b) * 64 + d;
    const float* vi = Vi + (n * 512 + b) * 64 + d;
    float oR[8], oI[8];
#pragma unroll
    for (int h = 0; h < 8; ++h) { oR[h] = 0.f; oI[h] = 0.f; }
    for (int pz = 0; pz < 32; ++pz) {
        int p = pp * 32 + pz;
        float xr = vr[p * 256];
        float xi = vi[p * 256];
#pragma unroll
        for (int h = 0; h < 8; ++h) {
            float a = sA[h * 132 + p];
            oR[h] = fmaf(a, xr, oR[h]);
            oI[h] = fmaf(a, xi, oI[h]);
        }
    }
    float* wb = sRed + pp * 1092;
#pragma unroll
    for (int s = 0; s < 16; ++s) {
        int h = s >> 1;
        wb[d * 17 + s] = (s & 1) ? oI[h] : oR[h];
    }
    __syncthreads();
    const int d2 = t & 63, g = t >> 6;
#pragma unroll
    for (int k = 0; k < 4; ++k) {
        int s = g * 4 + k;
        float v = sRed[0 * 1092 + d2 * 17 + s] + sRed[1 * 1092 + d2 * 17 + s]
                + sRed[2 * 1092 + d2 * 17 + s] + sRed[3 * 1092 + d2 * 17 + s];
        int h = s >> 1, ri = s & 1;
        out[(unsigned)ri * 524288u + ((n * 128 + q) * 4 + b) * 512u + h * 64 + d2] = v;
    }
}

// ---------------------------------------------------------------------------
extern "C" void kernel_launch(void* const* d_in, const int* in_sizes, int n_in,
                              void* d_out, int out_size, void* d_ws, size_t ws_size,
                              hipStream_t stream) {
    (void)in_sizes; (void)n_in; (void)out_size; (void)ws_size;
    const float* q_r  = (const float*)d_in[0];
    const float* q_i  = (const float*)d_in[1];
    const float* k_r  = (const float*)d_in[2];
    const float* k_i  = (const float*)d_in[3];
    const float* v_r  = (const float*)d_in[4];
    const float* v_i  = (const float*)d_in[5];
    const float* e_r  = (const float*)d_in[6];
    const float* e_i  = (const float*)d_in[7];
    const float* WKr_w  = (const float*)d_in[8];
    const float* WKi_w  = (const float*)d_in[10];
    const float* WKRr_w = (const float*)d_in[12];
    const float* WKRr_b = (const float*)d_in[13];
    const float* WKRi_w = (const float*)d_in[14];
    const float* WKRi_b = (const float*)d_in[15];
    const float* WQr_w  = (const float*)d_in[16];
    const float* WQi_w  = (const float*)d_in[18];
    const float* ww_r_g  = (const float*)d_in[20];
    const float* ww_r_bt = (const float*)d_in[21];
    const float* ww_i_g  = (const float*)d_in[22];
    const float* ww_i_bt = (const float*)d_in[23];
    const float* wr_r_g  = (const float*)d_in[24];
    const float* wr_r_bt = (const float*)d_in[25];
    const float* wr_i_g  = (const float*)d_in[26];
    const float* wr_i_bt = (const float*)d_in[27];
    float* ws  = (float*)d_ws;
    float* out = (float*)d_out;

    k_proj<<<dim3(16, 16, 2), 256, 0, stream>>>(q_r, q_i, k_r, k_i,
                                                WQr_w, WQi_w, WKr_w, WKi_w, ws);
    k_stats1<<<256, 256, 0, stream>>>(ws + WQ_R, ws + PART_);
    k_stats2<<<64, 64, 0, stream>>>(ws + PART_, ws + MU_, ws + RS_);
    k_vvec<<<dim3(32, 16), 256, 0, stream>>>(ws + WQ_R, ws + WQ_I, ws + MU_, ws + RS_,
                                             WKRr_w, WKRi_w, WKRr_b, WKRi_b,
                                             wr_r_g, wr_r_bt, wr_i_g, wr_i_bt,
                                             ws + VV_, ws + C_R_, ws + C_I_);
    k_ac<<<dim3(16, 16, 4), 256, 0, stream>>>(ws + WQ_R, ws + WQ_I, ws + WK_R, ws + WK_I,
                                              ws + MU_, ws + RS_,
                                              ww_r_g, ww_r_bt, ww_i_g, ww_i_bt,
                                              ws + ACR_, ws + ACI_);
    k_bd<<<dim3(8, 256), 256, 0, stream>>>(e_r, e_i, ws + VV_, ws + C_R_, ws + C_I_,
                                           ws + ACR_, ws + ACI_, ws + AFF_);
    k_pv<<<1024, 256, 0, stream>>>(ws + AFF_, v_r, v_i, out);
}